// Round 1
// 970.506 us; speedup vs baseline: 2.1340x; 2.1340x over previous
//
#include <hip/hip_runtime.h>

#define N_    64
#define C_    64
#define T_    300
#define V_    25
#define IC_   16
#define TV_   7500      // T*V
#define CTV_  480000    // C*T*V  (per-n x slice)
#define NB_   6400      // mega grid blocks (100 x 64)

typedef __attribute__((ext_vector_type(8))) short short8;
typedef __attribute__((ext_vector_type(4))) float f32x4;

static __device__ inline short f2bf(float f) {
    unsigned u = __float_as_uint(f);
    unsigned r = (u + 0x7fff + ((u >> 16) & 1)) >> 16;
    return (short)r;
}
static __device__ inline float bf2f(short s) {
    return __uint_as_float(((unsigned)(unsigned short)s) << 16);
}

// ---------------- A_mix: Chebyshev mix + column softmax ----------------
__global__ void amix_kernel(const float* __restrict__ A, const float* __restrict__ w,
                            float* __restrict__ amix) {
    int tid = threadIdx.x;
    if (tid >= 75) return;
    int s = tid / 25, col = tid % 25;
    const float* As = A + s * 625;
    float av[25], ch4[25];
#pragma unroll
    for (int r = 0; r < 25; ++r) {
        float a = As[r * 25 + col];
        float a2 = a * a;
        float eye = (r == col) ? 1.f : 0.f;
        av[r] = a;
        ch4[r] = 8.f * a2 * a2 - 8.f * a2 + eye;
    }
    float m = -1e30f;
#pragma unroll
    for (int r = 0; r < 25; ++r) m = fmaxf(m, ch4[r] * (1.f / 25.f));
    float e[25];
    float sum = 0.f;
#pragma unroll
    for (int r = 0; r < 25; ++r) { e[r] = __expf(ch4[r] * (1.f / 25.f) - m); sum += e[r]; }
    float inv = 1.f / sum;
    float w0 = w[0], w1 = w[1], w2 = w[2], w3 = w[3], w4 = w[4];
#pragma unroll
    for (int r = 0; r < 25; ++r) {
        float a = av[r], a2 = a * a;
        float eye = (r == col) ? 1.f : 0.f;
        amix[s * 625 + r * 25 + col] =
            w0 * a + w1 * (e[r] * inv) + w2 * ch4[r] +
            w3 * (4.f * a2 * a - 3.f * a) + w4 * (2.f * a2 - eye);
    }
}

// ---------------- weight prep, ALL 9 pairs in one launch ----------------
// wpk_all: per pair p, slot of 18432 shorts (taps*2048 used), A-frag order bf16.
// bpk: [pair][half][16] f32 biases.
__global__ void wprep_all(
    const float* __restrict__ a_w, const float* __restrict__ b_w,
    const float* __restrict__ t1_w, const float* __restrict__ t2_w,
    const float* __restrict__ st11_w1, const float* __restrict__ st12_w1,
    const float* __restrict__ st11_w9, const float* __restrict__ st12_w9,
    const float* __restrict__ a_b, const float* __restrict__ b_b,
    const float* __restrict__ t1_b, const float* __restrict__ t2_b,
    const float* __restrict__ st11_b, const float* __restrict__ st12_b,
    short* __restrict__ wpk_all, float* __restrict__ bpk) {
    int idx = blockIdx.x * 256 + threadIdx.x;
    int pair, r;
    bool bias_path = false;
    if (idx < 9 * 18432) {
        pair = idx / 18432; r = idx - pair * 18432;
    } else if (idx < 9 * 18432 + 288) {
        bias_path = true;
        int bidx = idx - 9 * 18432;
        pair = bidx >> 5; r = bidx & 31;
    } else return;

    const float *w1, *w2, *bb1, *bb2; int taps;
    switch (pair) {
        case 0: taps=1; w1=a_w;          w2=b_w;          bb1=a_b;       bb2=b_b;       break;
        case 1: taps=9; w1=t1_w;         w2=t2_w;         bb1=t1_b;      bb2=t2_b;      break;
        case 2: taps=1; w1=st11_w1;      w2=st12_w1;      bb1=st11_b;    bb2=st12_b;    break;
        case 3: taps=1; w1=a_w+1024;     w2=b_w+1024;     bb1=a_b+16;    bb2=b_b+16;    break;
        case 4: taps=9; w1=t1_w+9216;    w2=t2_w+9216;    bb1=t1_b+16;   bb2=t2_b+16;   break;
        case 5: taps=9; w1=st11_w9;      w2=st12_w9;      bb1=st11_b+16; bb2=st12_b+16; break;
        case 6: taps=1; w1=a_w+2048;     w2=b_w+2048;     bb1=a_b+32;    bb2=b_b+32;    break;
        case 7: taps=9; w1=t1_w+18432;   w2=t2_w+18432;   bb1=t1_b+32;   bb2=t2_b+32;   break;
        default: taps=1; w1=st11_w1+1024; w2=st12_w1+1024; bb1=st11_b+32; bb2=st12_b+32; break;
    }
    if (bias_path) {
        int half = r >> 4, o = r & 15;
        bpk[pair * 32 + r] = half ? bb2[o] : bb1[o];
        return;
    }
    if (r >= taps * 2048) return;
    int j = r & 7;
    int l = (r >> 3) & 63;
    int half = (r >> 9) & 1;
    int kk = r >> 10;
    int K = kk * 32 + ((l >> 4) << 3) + j;
    int c = K & 63, k = K >> 6;
    int o = l & 15;
    const float* w = half ? w2 : w1;
    wpk_all[pair * 18432 + r] = f2bf(w[(o * 64 + c) * taps + k]);
}

// ---------------- dw prep: 12 m-tiles, K = c (64), bf16 A-frags ----------------
__global__ void dwprep(const float* __restrict__ dw, const float* __restrict__ db,
                       short* __restrict__ dwpk, float* __restrict__ db_sum) {
    int idx = blockIdx.x * 256 + threadIdx.x;
    if (idx < 12288) {
        int j = idx & 7;
        int lane = (idx >> 3) & 63;
        int kk = (idx >> 9) & 1;
        int mt = idx >> 10;
        int R = mt * 16 + (lane & 15);
        int c = kk * 32 + ((lane >> 4) << 3) + j;
        int i = R >> 6, o = R & 63;
        dwpk[idx] = f2bf(dw[i * 4096 + o * 64 + c]);
    }
    if (idx < 64) db_sum[idx] = db[idx] + db[64 + idx] + db[128 + idx];
}

// ---------------- fused conv + gram: all 9 pairs, one x staging ----------------
// Block = (chunk of 5 t = 125 positions, n). Window = 13 t (pad to 328 rows).
// Per pair: conv (MFMA, acc in regs) -> fT[v][k=tl*16+ic] bf16 in LDS ->
// gram G = f1^T f2 via 3 MFMAs per wave quadrant -> bf16 partial to Gpart.
template <int TAPS>
static __device__ inline void conv_do(const short* __restrict__ wp,
                                      const short* xs, int pw, int lane,
                                      f32x4 acc[2][2]) {
    int q = lane >> 4, m = lane & 15;
#pragma unroll
    for (int kk = 0; kk < 2 * TAPS; ++kk) {
        int k = kk >> 1;
        int c0 = (kk & 1) * 32;
        short8 a0 = *(const short8*)(wp + ((kk * 2 + 0) * 64 + lane) * 8);
        short8 a1 = *(const short8*)(wp + ((kk * 2 + 1) * 64 + lane) * 8);
        int rbase = 100 + pw + m + (k - TAPS / 2) * 25;
        short8 b0 = *(const short8*)(xs + rbase * 72 + c0 + q * 8);
        short8 b1 = *(const short8*)(xs + (rbase + 16) * 72 + c0 + q * 8);
        acc[0][0] = __builtin_amdgcn_mfma_f32_16x16x32_bf16(a0, b0, acc[0][0], 0, 0, 0);
        acc[0][1] = __builtin_amdgcn_mfma_f32_16x16x32_bf16(a0, b1, acc[0][1], 0, 0, 0);
        acc[1][0] = __builtin_amdgcn_mfma_f32_16x16x32_bf16(a1, b0, acc[1][0], 0, 0, 0);
        acc[1][1] = __builtin_amdgcn_mfma_f32_16x16x32_bf16(a1, b1, acc[1][1], 0, 0, 0);
    }
}

__global__ __launch_bounds__(256) void convgram(
    const float* __restrict__ x, const short* __restrict__ wpk_all,
    const float* __restrict__ bpk, short* __restrict__ Gpart) {
    __shared__ __align__(16) short xs[328 * 72];     // 47,232 B
    __shared__ __align__(16) short fT[2 * 32 * 104]; // 13,312 B ([h][v pad32][k pad96->104])
    int tid = threadIdx.x;
    int n = blockIdx.y, ch = blockIdx.x;
    int p0 = ch * 125;
    const float* xn = x + n * CTV_;
    for (int jj = tid; jj < 64 * 328; jj += 256) {
        int c = jj / 328, rr = jj - c * 328;
        int pp = p0 - 100 + rr;
        float v = (pp >= 0 && pp < TV_) ? xn[c * TV_ + pp] : 0.f;
        xs[rr * 72 + c] = f2bf(v);
    }
    // zero fT once (K-pad [80,96) and v rows [25,32) must stay 0 across all pairs)
    for (int jj = tid; jj < 3328; jj += 256) ((int*)fT)[jj] = 0;
    __syncthreads();

    int wave = tid >> 6, lane = tid & 63, q = lane >> 4, m = lane & 15;
    int pw = wave * 32;
    int mt = wave >> 1, ntl = wave & 1;   // gram quadrant per wave

    for (int pair = 0; pair < 9; ++pair) {
        bool nine = (pair == 1) || (pair == 4) || (pair == 5) || (pair == 7);
        const short* wp = wpk_all + pair * 18432;
        f32x4 acc[2][2];
#pragma unroll
        for (int h = 0; h < 2; ++h)
#pragma unroll
            for (int nt = 0; nt < 2; ++nt) acc[h][nt] = (f32x4)(0.f);
        if (nine) conv_do<9>(wp, xs, pw, lane, acc);
        else      conv_do<1>(wp, xs, pw, lane, acc);

        __syncthreads();  // previous pair's gram reads of fT are done
#pragma unroll
        for (int h = 0; h < 2; ++h) {
#pragma unroll
            for (int nt = 0; nt < 2; ++nt) {
                int p = pw + nt * 16 + m;
                if (p < 125) {
                    int tl = p / 25, v = p - tl * 25;
#pragma unroll
                    for (int r = 0; r < 4; ++r) {
                        int o = q * 4 + r;
                        fT[h * 3328 + v * 104 + tl * 16 + o] =
                            f2bf(acc[h][nt][r] + bpk[pair * 32 + h * 16 + o]);
                    }
                }
            }
        }
        __syncthreads();  // fT ready

        // gram: G[v][v'] = sum_k f1[v][k] f2[v'][k], K=80 (pad 96), 3 MFMAs
        f32x4 g = (f32x4)(0.f);
#pragma unroll
        for (int s = 0; s < 3; ++s) {
            short8 af = *(const short8*)(fT + (mt * 16 + m) * 104 + s * 32 + q * 8);
            short8 bf = *(const short8*)(fT + 3328 + (ntl * 16 + m) * 104 + s * 32 + q * 8);
            g = __builtin_amdgcn_mfma_f32_16x16x32_bf16(af, bf, g, 0, 0, 0);
        }
        int gvp = ntl * 16 + m;
        if (gvp < 25) {
            short* gdst = Gpart + ((pair * 60 + ch) * 64 + n) * 625 + gvp;
#pragma unroll
            for (int r = 0; r < 4; ++r) {
                int v = mt * 16 + q * 4 + r;
                if (v < 25) gdst[v * 25] = f2bf(g[r]);
            }
        }
    }
}

// ---------------- gram finalize: sum chunks + column softmax, all 9 pairs ----------------
__global__ __launch_bounds__(256) void gram_finalize_all(
    const short* __restrict__ Gpart, float* __restrict__ S) {
    __shared__ float sm[625];
    int n = blockIdx.x, pair = blockIdx.y;
    int tid = threadIdx.x;
    for (int qq = tid; qq < 625; qq += 256) {
        float s = 0.f;
        for (int ch = 0; ch < 60; ++ch)
            s += bf2f(Gpart[((pair * 60 + ch) * 64 + n) * 625 + qq]);
        sm[qq] = s * (1.f / 4800.f);
    }
    __syncthreads();
    if (tid < 25) {
        int col = tid;
        float m = -1e30f;
#pragma unroll
        for (int r = 0; r < 25; ++r) m = fmaxf(m, sm[r * 25 + col]);
        float e[25];
        float sum = 0.f;
#pragma unroll
        for (int r = 0; r < 25; ++r) { e[r] = __expf(sm[r * 25 + col] - m); sum += e[r]; }
        float inv = 1.f / sum;
#pragma unroll
        for (int r = 0; r < 25; ++r)
            S[pair * 40000 + n * 625 + r * 25 + col] = e[r] * inv;
    }
}

// ---------------- mega: y = sum_i (dw_i @ x) @ Ai, all subsets, + BN partials ----------------
__global__ __launch_bounds__(256) void mega(
    const float* __restrict__ x, const float* __restrict__ amix,
    const float* __restrict__ S, const float* __restrict__ wts,
    const short* __restrict__ dwpk, const float* __restrict__ db_sum,
    float* __restrict__ out, float* __restrict__ partials) {
    __shared__ __align__(16) short xs[80 * 72];       // [p][c] bf16, stride 72
    __shared__ __align__(16) short us[3 * 64 * 104];  // [t][o][K=96 pad 104] bf16
    __shared__ __align__(16) short Aib[3 * 32 * 40];  // [i][v][vp pad 40] bf16

    int tid = threadIdx.x;
    int n = blockIdx.y;
    int t0 = blockIdx.x * 3;
    const float* xn = x + n * CTV_ + t0 * 25;

    for (int jj = tid; jj < 64 * 80; jj += 256) {
        int c = jj / 80, p = jj - c * 80;
        float v = (p < 75) ? xn[c * TV_ + p] : 0.f;
        xs[p * 72 + c] = f2bf(v);
    }
    for (int jj = tid; jj < 3 * 64 * 52; jj += 256) ((int*)us)[jj] = 0;
    float w5 = wts[5], w6 = wts[6], w7 = wts[7];
    for (int jj = tid; jj < 3840; jj += 256) {
        int i = jj / 1280;
        int rem = jj - i * 1280;
        int v = rem / 40, vp = rem - v * 40;
        float val = 0.f;
        if (v < 25 && vp < 25) {
            int e = vp * 25 + v;
            val = amix[i * 625 + e]
                + w5 * S[(i * 3 + 0) * 40000 + n * 625 + e]
                + w6 * S[(i * 3 + 1) * 40000 + n * 625 + e]
                + w7 * S[(i * 3 + 2) * 40000 + n * 625 + e];
        }
        Aib[jj] = f2bf(val);
    }

    int wave = tid >> 6, lane = tid & 63;
    int q = lane >> 4, m = lane & 15;

    short8 af[3][2];
#pragma unroll
    for (int mt = 0; mt < 3; ++mt)
#pragma unroll
        for (int kk = 0; kk < 2; ++kk)
            af[mt][kk] = *(const short8*)(dwpk + ((wave * 3 + mt) * 2 + kk) * 512 + lane * 8);
    float db4[4];
#pragma unroll
    for (int r = 0; r < 4; ++r) db4[r] = db_sum[wave * 16 + q * 4 + r];

    __syncthreads();

    f32x4 acc[3][5];
#pragma unroll
    for (int mt = 0; mt < 3; ++mt)
#pragma unroll
        for (int nt = 0; nt < 5; ++nt) acc[mt][nt] = (f32x4)(0.f);

#pragma unroll
    for (int nt = 0; nt < 5; ++nt) {
        short8 b0 = *(const short8*)(xs + (nt * 16 + m) * 72 + q * 8);
        short8 b1 = *(const short8*)(xs + (nt * 16 + m) * 72 + 32 + q * 8);
#pragma unroll
        for (int mt = 0; mt < 3; ++mt) {
            acc[mt][nt] = __builtin_amdgcn_mfma_f32_16x16x32_bf16(af[mt][0], b0, acc[mt][nt], 0, 0, 0);
            acc[mt][nt] = __builtin_amdgcn_mfma_f32_16x16x32_bf16(af[mt][1], b1, acc[mt][nt], 0, 0, 0);
        }
    }
#pragma unroll
    for (int nt = 0; nt < 5; ++nt) {
        int p = nt * 16 + m;
        if (p < 75) {
            int t = p / 25, vp = p - t * 25;
            int base = t * 6656 + vp;
#pragma unroll
            for (int mt = 0; mt < 3; ++mt) {
#pragma unroll
                for (int r = 0; r < 4; ++r) {
                    int R = wave * 48 + mt * 16 + q * 4 + r;
                    int i = R >> 6, o = R & 63;
                    us[base + o * 104 + i * 32] = f2bf(acc[mt][nt][r]);
                }
            }
        }
    }
    __syncthreads();

    short8 bfr[3][2];
#pragma unroll
    for (int i = 0; i < 3; ++i)
#pragma unroll
        for (int nt = 0; nt < 2; ++nt)
            bfr[i][nt] = *(const short8*)(Aib + (i * 32 + nt * 16 + m) * 40 + q * 8);

    float sr[4] = {0.f, 0.f, 0.f, 0.f}, s2r[4] = {0.f, 0.f, 0.f, 0.f};
    float* yb = out + n * CTV_ + t0 * 25;
#pragma unroll
    for (int t = 0; t < 3; ++t) {
        f32x4 a2[2];
        a2[0] = (f32x4)(0.f);
        a2[1] = (f32x4)(0.f);
#pragma unroll
        for (int i = 0; i < 3; ++i) {
            short8 ua = *(const short8*)(us + t * 6656 + (wave * 16 + m) * 104 + i * 32 + q * 8);
            a2[0] = __builtin_amdgcn_mfma_f32_16x16x32_bf16(ua, bfr[i][0], a2[0], 0, 0, 0);
            a2[1] = __builtin_amdgcn_mfma_f32_16x16x32_bf16(ua, bfr[i][1], a2[1], 0, 0, 0);
        }
#pragma unroll
        for (int nt = 0; nt < 2; ++nt) {
            int v = nt * 16 + m;
            if (v < 25) {
#pragma unroll
                for (int r = 0; r < 4; ++r) {
                    int o = wave * 16 + q * 4 + r;
                    float val = a2[nt][r] + db4[r];
                    yb[o * TV_ + t * 25 + v] = val;
                    sr[r] += val;
                    s2r[r] += val * val;
                }
            }
        }
    }

    int bid = blockIdx.y * 100 + blockIdx.x;
#pragma unroll
    for (int r = 0; r < 4; ++r) {
        float s = sr[r], s2 = s2r[r];
#pragma unroll
        for (int d = 1; d < 16; d <<= 1) {
            s += __shfl_xor(s, d, 64);
            s2 += __shfl_xor(s2, d, 64);
        }
        if (m == 0) {
            int o = wave * 16 + q * 4 + r;
            partials[o * NB_ + bid] = s;
            partials[(64 + o) * NB_ + bid] = s2;
        }
    }
}

// ---------------- BN stats: sum partials ----------------
__global__ __launch_bounds__(256) void bn_stats(const float* __restrict__ partials,
                                                float* __restrict__ stats) {
    int j = blockIdx.x;
    int tid = threadIdx.x;
    float s = 0.f;
    for (int idx = tid; idx < NB_; idx += 256) s += partials[j * NB_ + idx];
    for (int d = 32; d > 0; d >>= 1) s += __shfl_down(s, d, 64);
    __shared__ float ls[4];
    if ((tid & 63) == 0) ls[tid >> 6] = s;
    __syncthreads();
    if (tid == 0) stats[j] = ls[0] + ls[1] + ls[2] + ls[3];
}

// ---------------- BN apply + residual + relu, float4 (TV_ % 4 == 0) ----------------
__global__ __launch_bounds__(256) void bn_final4(
    const float* __restrict__ x, const float* __restrict__ stats,
    const float* __restrict__ bnw, const float* __restrict__ bnb,
    float* __restrict__ y) {
    int idx = blockIdx.x * 256 + threadIdx.x;   // 7,680,000 float4s
    int o = (idx / 1875) & 63;                  // TV_/4 = 1875
    const float cnt = (float)(N_ * TV_);
    float mu = stats[o] / cnt;
    float var = stats[64 + o] / cnt - mu * mu;
    float inv = rsqrtf(var + 1e-5f);
    float w = bnw[o], b = bnb[o];
    f32x4 yv = ((const f32x4*)y)[idx];
    f32x4 xv = ((const f32x4*)x)[idx];
    f32x4 r;
#pragma unroll
    for (int k = 0; k < 4; ++k) r[k] = fmaxf((yv[k] - mu) * inv * w + b + xv[k], 0.f);
    ((f32x4*)y)[idx] = r;
}

extern "C" void kernel_launch(void* const* d_in, const int* in_sizes, int n_in,
                              void* d_out, int out_size, void* d_ws, size_t ws_size,
                              hipStream_t stream) {
    (void)in_sizes; (void)n_in; (void)out_size; (void)ws_size;
    const float* x     = (const float*)d_in[0];
    const float* wts   = (const float*)d_in[1];
    const float* A     = (const float*)d_in[2];
    const float* a_w   = (const float*)d_in[3];
    const float* a_b   = (const float*)d_in[4];
    const float* b_w   = (const float*)d_in[5];
    const float* b_b   = (const float*)d_in[6];
    const float* d_wp  = (const float*)d_in[7];
    const float* d_bp  = (const float*)d_in[8];
    const float* t1_w  = (const float*)d_in[9];
    const float* t1_b  = (const float*)d_in[10];
    const float* t2_w  = (const float*)d_in[11];
    const float* t2_b  = (const float*)d_in[12];
    const float* st11_w1 = (const float*)d_in[13];
    const float* st11_w9 = (const float*)d_in[14];
    const float* st11_b  = (const float*)d_in[15];
    const float* st12_w1 = (const float*)d_in[16];
    const float* st12_w9 = (const float*)d_in[17];
    const float* st12_b  = (const float*)d_in[18];
    const float* bn_w  = (const float*)d_in[19];
    const float* bn_b  = (const float*)d_in[20];
    float* out = (float*)d_out;

    // ---- workspace layout (disjoint; max end ~49.4 MB < previous 64.3 MB footprint) ----
    // amix      [0         , 7,500)
    // stats     [8,192     , 8,704)
    // db_sum    [12,288    , 12,544)
    // S         [16,384    , 1,456,384)     9 slabs x 160,000 B
    // dwpk      [1,460,224 , 1,484,800)
    // bpk       [1,486,848 , 1,488,000)     9 x 32 f32 biases
    // wpk_all   [1,490,944 , 1,822,720)     9 x 18432 bf16
    // Gpart     [2,097,152 , 45,297,152)    bf16 [9][60][64][625]
    // partials  [46,137,344, 49,414,144)    128 x 6400 f32
    char* ws = (char*)d_ws;
    float* amix     = (float*)(ws);
    float* stats    = (float*)(ws + 8192);
    float* db_sum   = (float*)(ws + 12288);
    float* S        = (float*)(ws + 16384);
    short* dwpk     = (short*)(ws + 1460224);
    float* bpk      = (float*)(ws + 1486848);
    short* wpk_all  = (short*)(ws + 1490944);
    short* Gpart    = (short*)(ws + 2097152);
    float* partials = (float*)(ws + 46137344);

    amix_kernel<<<1, 128, 0, stream>>>(A, wts, amix);
    dwprep<<<48, 256, 0, stream>>>(d_wp, d_bp, dwpk, db_sum);
    wprep_all<<<650, 256, 0, stream>>>(a_w, b_w, t1_w, t2_w, st11_w1, st12_w1,
                                       st11_w9, st12_w9, a_b, b_b, t1_b, t2_b,
                                       st11_b, st12_b, wpk_all, bpk);
    convgram<<<dim3(60, 64), 256, 0, stream>>>(x, wpk_all, bpk, Gpart);
    gram_finalize_all<<<dim3(64, 9), 256, 0, stream>>>(Gpart, S);
    mega<<<dim3(100, 64), 256, 0, stream>>>(x, amix, S, wts, dwpk, db_sum, out, partials);
    bn_stats<<<128, 256, 0, stream>>>(partials, stats);
    bn_final4<<<30000, 256, 0, stream>>>(x, stats, bn_w, bn_b, out);
}

// Round 2
// 969.461 us; speedup vs baseline: 2.1363x; 1.0011x over previous
//
#include <hip/hip_runtime.h>

#define N_    64
#define C_    64
#define T_    300
#define V_    25
#define IC_   16
#define TV_   7500      // T*V
#define CTV_  480000    // C*T*V  (per-n x slice)
#define NB_   6400      // mega grid blocks (100 x 64)

typedef __attribute__((ext_vector_type(8))) short short8;
typedef __attribute__((ext_vector_type(4))) float f32x4;

static __device__ inline short f2bf(float f) {
    unsigned u = __float_as_uint(f);
    unsigned r = (u + 0x7fff + ((u >> 16) & 1)) >> 16;
    return (short)r;
}
static __device__ inline float bf2f(short s) {
    return __uint_as_float(((unsigned)(unsigned short)s) << 16);
}

// ---------------- A_mix: Chebyshev mix + column softmax ----------------
__global__ void amix_kernel(const float* __restrict__ A, const float* __restrict__ w,
                            float* __restrict__ amix) {
    int tid = threadIdx.x;
    if (tid >= 75) return;
    int s = tid / 25, col = tid % 25;
    const float* As = A + s * 625;
    float av[25], ch4[25];
#pragma unroll
    for (int r = 0; r < 25; ++r) {
        float a = As[r * 25 + col];
        float a2 = a * a;
        float eye = (r == col) ? 1.f : 0.f;
        av[r] = a;
        ch4[r] = 8.f * a2 * a2 - 8.f * a2 + eye;
    }
    float m = -1e30f;
#pragma unroll
    for (int r = 0; r < 25; ++r) m = fmaxf(m, ch4[r] * (1.f / 25.f));
    float e[25];
    float sum = 0.f;
#pragma unroll
    for (int r = 0; r < 25; ++r) { e[r] = __expf(ch4[r] * (1.f / 25.f) - m); sum += e[r]; }
    float inv = 1.f / sum;
    float w0 = w[0], w1 = w[1], w2 = w[2], w3 = w[3], w4 = w[4];
#pragma unroll
    for (int r = 0; r < 25; ++r) {
        float a = av[r], a2 = a * a;
        float eye = (r == col) ? 1.f : 0.f;
        amix[s * 625 + r * 25 + col] =
            w0 * a + w1 * (e[r] * inv) + w2 * ch4[r] +
            w3 * (4.f * a2 * a - 3.f * a) + w4 * (2.f * a2 - eye);
    }
}

// ---------------- weight prep, ALL 9 pairs in one launch ----------------
// wpk_all: per pair p, slot of 18432 shorts (taps*2048 used), A-frag order bf16.
// bpk: [pair][half][16] f32 biases.
__global__ void wprep_all(
    const float* __restrict__ a_w, const float* __restrict__ b_w,
    const float* __restrict__ t1_w, const float* __restrict__ t2_w,
    const float* __restrict__ st11_w1, const float* __restrict__ st12_w1,
    const float* __restrict__ st11_w9, const float* __restrict__ st12_w9,
    const float* __restrict__ a_b, const float* __restrict__ b_b,
    const float* __restrict__ t1_b, const float* __restrict__ t2_b,
    const float* __restrict__ st11_b, const float* __restrict__ st12_b,
    short* __restrict__ wpk_all, float* __restrict__ bpk) {
    int idx = blockIdx.x * 256 + threadIdx.x;
    int pair, r;
    bool bias_path = false;
    if (idx < 9 * 18432) {
        pair = idx / 18432; r = idx - pair * 18432;
    } else if (idx < 9 * 18432 + 288) {
        bias_path = true;
        int bidx = idx - 9 * 18432;
        pair = bidx >> 5; r = bidx & 31;
    } else return;

    const float *w1, *w2, *bb1, *bb2; int taps;
    switch (pair) {
        case 0: taps=1; w1=a_w;          w2=b_w;          bb1=a_b;       bb2=b_b;       break;
        case 1: taps=9; w1=t1_w;         w2=t2_w;         bb1=t1_b;      bb2=t2_b;      break;
        case 2: taps=1; w1=st11_w1;      w2=st12_w1;      bb1=st11_b;    bb2=st12_b;    break;
        case 3: taps=1; w1=a_w+1024;     w2=b_w+1024;     bb1=a_b+16;    bb2=b_b+16;    break;
        case 4: taps=9; w1=t1_w+9216;    w2=t2_w+9216;    bb1=t1_b+16;   bb2=t2_b+16;   break;
        case 5: taps=9; w1=st11_w9;      w2=st12_w9;      bb1=st11_b+16; bb2=st12_b+16; break;
        case 6: taps=1; w1=a_w+2048;     w2=b_w+2048;     bb1=a_b+32;    bb2=b_b+32;    break;
        case 7: taps=9; w1=t1_w+18432;   w2=t2_w+18432;   bb1=t1_b+32;   bb2=t2_b+32;   break;
        default: taps=1; w1=st11_w1+1024; w2=st12_w1+1024; bb1=st11_b+32; bb2=st12_b+32; break;
    }
    if (bias_path) {
        int half = r >> 4, o = r & 15;
        bpk[pair * 32 + r] = half ? bb2[o] : bb1[o];
        return;
    }
    if (r >= taps * 2048) return;
    int j = r & 7;
    int l = (r >> 3) & 63;
    int half = (r >> 9) & 1;
    int kk = r >> 10;
    int K = kk * 32 + ((l >> 4) << 3) + j;
    int c = K & 63, k = K >> 6;
    int o = l & 15;
    const float* w = half ? w2 : w1;
    wpk_all[pair * 18432 + r] = f2bf(w[(o * 64 + c) * taps + k]);
}

// ---------------- dw prep: 12 m-tiles, K = c (64), bf16 A-frags ----------------
__global__ void dwprep(const float* __restrict__ dw, const float* __restrict__ db,
                       short* __restrict__ dwpk, float* __restrict__ db_sum) {
    int idx = blockIdx.x * 256 + threadIdx.x;
    if (idx < 12288) {
        int j = idx & 7;
        int lane = (idx >> 3) & 63;
        int kk = (idx >> 9) & 1;
        int mt = idx >> 10;
        int R = mt * 16 + (lane & 15);
        int c = kk * 32 + ((lane >> 4) << 3) + j;
        int i = R >> 6, o = R & 63;
        dwpk[idx] = f2bf(dw[i * 4096 + o * 64 + c]);
    }
    if (idx < 64) db_sum[idx] = db[idx] + db[64 + idx] + db[128 + idx];
}

// ---------------- fused conv + gram: all 9 pairs, acc-in-regs, barrier-free conv ----------------
// Block = (chunk of 5 t = 125 positions, n). Window = 13 t (328 rows).
// Conv phase: single pass over 18 (tap,c0) combos; b-frags loaded once, all
// active pairs' MFMAs fired back-to-back; acc[9][2][2] lives in registers.
// Epilogue: per pair, write fT (double-buffered), 1 barrier, gram (3 MFMAs per
// wave quadrant), bf16 partial to Gpart.
__global__ __launch_bounds__(256, 2) void convgram(
    const float* __restrict__ x, const short* __restrict__ wpk_all,
    const float* __restrict__ bpk, short* __restrict__ Gpart) {
    __shared__ __align__(16) short xs[328 * 72];      // 47,232 B
    __shared__ __align__(16) short fTb[2 * 6656];     // 2 x 13,312 B dbuf ([h][v pad32][k pad96->104])
    int tid = threadIdx.x;
    int n = blockIdx.y, ch = blockIdx.x;
    int p0 = ch * 125;
    const float* xn = x + n * CTV_;
    for (int jj = tid; jj < 64 * 328; jj += 256) {
        int c = jj / 328, rr = jj - c * 328;
        int pp = p0 - 100 + rr;
        float v = (pp >= 0 && pp < TV_) ? xn[c * TV_ + pp] : 0.f;
        xs[rr * 72 + c] = f2bf(v);
    }
    // zero both fT buffers (K-pad [80,96) and v rows [25,32) must stay 0)
    for (int jj = tid; jj < 6656; jj += 256) ((int*)fTb)[jj] = 0;
    __syncthreads();

    int wave = tid >> 6, lane = tid & 63, q = lane >> 4, m = lane & 15;
    int pw = wave * 32;
    int mt = wave >> 1, ntl = wave & 1;   // gram quadrant per wave

    f32x4 acc[9][2][2];
#pragma unroll
    for (int p = 0; p < 9; ++p)
#pragma unroll
        for (int h = 0; h < 2; ++h)
#pragma unroll
            for (int nt = 0; nt < 2; ++nt) acc[p][h][nt] = (f32x4)(0.f);

    // ---- conv phase: no barriers, shared b-frags, all pairs ----
#pragma unroll
    for (int kc = 0; kc < 18; ++kc) {
        const int k = kc >> 1;
        const int c0 = (kc & 1) * 32;
        // rbase = 100 + pw + m + (k-4)*25 = pw + m + 25k
        short8 b0 = *(const short8*)(xs + (pw + m + 25 * k) * 72 + c0 + q * 8);
        short8 b1 = *(const short8*)(xs + (pw + m + 25 * k + 16) * 72 + c0 + q * 8);
        const int NP[4] = {1, 4, 5, 7};     // nine-tap pairs
#pragma unroll
        for (int pi = 0; pi < 4; ++pi) {
            const short* wp = wpk_all + NP[pi] * 18432 + kc * 1024 + lane * 8;
            short8 a0 = *(const short8*)(wp);
            short8 a1 = *(const short8*)(wp + 512);
            acc[NP[pi]][0][0] = __builtin_amdgcn_mfma_f32_16x16x32_bf16(a0, b0, acc[NP[pi]][0][0], 0, 0, 0);
            acc[NP[pi]][0][1] = __builtin_amdgcn_mfma_f32_16x16x32_bf16(a0, b1, acc[NP[pi]][0][1], 0, 0, 0);
            acc[NP[pi]][1][0] = __builtin_amdgcn_mfma_f32_16x16x32_bf16(a1, b0, acc[NP[pi]][1][0], 0, 0, 0);
            acc[NP[pi]][1][1] = __builtin_amdgcn_mfma_f32_16x16x32_bf16(a1, b1, acc[NP[pi]][1][1], 0, 0, 0);
        }
        if (k == 4) {                       // one-tap pairs, center tap only
            const int OP[5] = {0, 2, 3, 6, 8};
#pragma unroll
            for (int pi = 0; pi < 5; ++pi) {
                const short* wp = wpk_all + OP[pi] * 18432 + (kc & 1) * 1024 + lane * 8;
                short8 a0 = *(const short8*)(wp);
                short8 a1 = *(const short8*)(wp + 512);
                acc[OP[pi]][0][0] = __builtin_amdgcn_mfma_f32_16x16x32_bf16(a0, b0, acc[OP[pi]][0][0], 0, 0, 0);
                acc[OP[pi]][0][1] = __builtin_amdgcn_mfma_f32_16x16x32_bf16(a0, b1, acc[OP[pi]][0][1], 0, 0, 0);
                acc[OP[pi]][1][0] = __builtin_amdgcn_mfma_f32_16x16x32_bf16(a1, b0, acc[OP[pi]][1][0], 0, 0, 0);
                acc[OP[pi]][1][1] = __builtin_amdgcn_mfma_f32_16x16x32_bf16(a1, b1, acc[OP[pi]][1][1], 0, 0, 0);
            }
        }
    }

    // ---- epilogue: per pair, fT dbuf write -> barrier -> gram -> Gpart ----
#pragma unroll
    for (int pair = 0; pair < 9; ++pair) {
        short* fb = fTb + (pair & 1) * 6656;
        f32x4 bh0 = *(const f32x4*)(bpk + pair * 32 + q * 4);
        f32x4 bh1 = *(const f32x4*)(bpk + pair * 32 + 16 + q * 4);
#pragma unroll
        for (int h = 0; h < 2; ++h) {
#pragma unroll
            for (int nt = 0; nt < 2; ++nt) {
                int p = pw + nt * 16 + m;
                if (p < 125) {
                    int tl = p / 25, v = p - tl * 25;
#pragma unroll
                    for (int r = 0; r < 4; ++r) {
                        float bv = h ? bh1[r] : bh0[r];
                        fb[h * 3328 + v * 104 + tl * 16 + q * 4 + r] =
                            f2bf(acc[pair][h][nt][r] + bv);
                    }
                }
            }
        }
        __syncthreads();   // fb ready; prior pair's gram used the other buffer

        f32x4 g = (f32x4)(0.f);
#pragma unroll
        for (int s = 0; s < 3; ++s) {
            short8 af = *(const short8*)(fb + (mt * 16 + m) * 104 + s * 32 + q * 8);
            short8 bf = *(const short8*)(fb + 3328 + (ntl * 16 + m) * 104 + s * 32 + q * 8);
            g = __builtin_amdgcn_mfma_f32_16x16x32_bf16(af, bf, g, 0, 0, 0);
        }
        int gvp = ntl * 16 + m;
        if (gvp < 25) {
            short* gdst = Gpart + ((pair * 60 + ch) * 64 + n) * 625 + gvp;
#pragma unroll
            for (int r = 0; r < 4; ++r) {
                int v = mt * 16 + q * 4 + r;
                if (v < 25) gdst[v * 25] = f2bf(g[r]);
            }
        }
    }
}

// ---------------- gram finalize: sum chunks + column softmax, all 9 pairs ----------------
__global__ __launch_bounds__(256) void gram_finalize_all(
    const short* __restrict__ Gpart, float* __restrict__ S) {
    __shared__ float sm[625];
    int n = blockIdx.x, pair = blockIdx.y;
    int tid = threadIdx.x;
    for (int qq = tid; qq < 625; qq += 256) {
        float s = 0.f;
        for (int ch = 0; ch < 60; ++ch)
            s += bf2f(Gpart[((pair * 60 + ch) * 64 + n) * 625 + qq]);
        sm[qq] = s * (1.f / 4800.f);
    }
    __syncthreads();
    if (tid < 25) {
        int col = tid;
        float m = -1e30f;
#pragma unroll
        for (int r = 0; r < 25; ++r) m = fmaxf(m, sm[r * 25 + col]);
        float e[25];
        float sum = 0.f;
#pragma unroll
        for (int r = 0; r < 25; ++r) { e[r] = __expf(sm[r * 25 + col] - m); sum += e[r]; }
        float inv = 1.f / sum;
#pragma unroll
        for (int r = 0; r < 25; ++r)
            S[pair * 40000 + n * 625 + r * 25 + col] = e[r] * inv;
    }
}

// ---------------- mega: y = sum_i (dw_i @ x) @ Ai, all subsets, + BN partials ----------------
__global__ __launch_bounds__(256) void mega(
    const float* __restrict__ x, const float* __restrict__ amix,
    const float* __restrict__ S, const float* __restrict__ wts,
    const short* __restrict__ dwpk, const float* __restrict__ db_sum,
    float* __restrict__ out, float* __restrict__ partials) {
    __shared__ __align__(16) short xs[80 * 72];       // [p][c] bf16, stride 72
    __shared__ __align__(16) short us[3 * 64 * 104];  // [t][o][K=96 pad 104] bf16
    __shared__ __align__(16) short Aib[3 * 32 * 40];  // [i][v][vp pad 40] bf16

    int tid = threadIdx.x;
    int n = blockIdx.y;
    int t0 = blockIdx.x * 3;
    const float* xn = x + n * CTV_ + t0 * 25;

    for (int jj = tid; jj < 64 * 80; jj += 256) {
        int c = jj / 80, p = jj - c * 80;
        float v = (p < 75) ? xn[c * TV_ + p] : 0.f;
        xs[p * 72 + c] = f2bf(v);
    }
    for (int jj = tid; jj < 3 * 64 * 52; jj += 256) ((int*)us)[jj] = 0;
    float w5 = wts[5], w6 = wts[6], w7 = wts[7];
    for (int jj = tid; jj < 3840; jj += 256) {
        int i = jj / 1280;
        int rem = jj - i * 1280;
        int v = rem / 40, vp = rem - v * 40;
        float val = 0.f;
        if (v < 25 && vp < 25) {
            int e = vp * 25 + v;
            val = amix[i * 625 + e]
                + w5 * S[(i * 3 + 0) * 40000 + n * 625 + e]
                + w6 * S[(i * 3 + 1) * 40000 + n * 625 + e]
                + w7 * S[(i * 3 + 2) * 40000 + n * 625 + e];
        }
        Aib[jj] = f2bf(val);
    }

    int wave = tid >> 6, lane = tid & 63;
    int q = lane >> 4, m = lane & 15;

    short8 af[3][2];
#pragma unroll
    for (int mt = 0; mt < 3; ++mt)
#pragma unroll
        for (int kk = 0; kk < 2; ++kk)
            af[mt][kk] = *(const short8*)(dwpk + ((wave * 3 + mt) * 2 + kk) * 512 + lane * 8);
    float db4[4];
#pragma unroll
    for (int r = 0; r < 4; ++r) db4[r] = db_sum[wave * 16 + q * 4 + r];

    __syncthreads();

    f32x4 acc[3][5];
#pragma unroll
    for (int mt = 0; mt < 3; ++mt)
#pragma unroll
        for (int nt = 0; nt < 5; ++nt) acc[mt][nt] = (f32x4)(0.f);

#pragma unroll
    for (int nt = 0; nt < 5; ++nt) {
        short8 b0 = *(const short8*)(xs + (nt * 16 + m) * 72 + q * 8);
        short8 b1 = *(const short8*)(xs + (nt * 16 + m) * 72 + 32 + q * 8);
#pragma unroll
        for (int mt = 0; mt < 3; ++mt) {
            acc[mt][nt] = __builtin_amdgcn_mfma_f32_16x16x32_bf16(af[mt][0], b0, acc[mt][nt], 0, 0, 0);
            acc[mt][nt] = __builtin_amdgcn_mfma_f32_16x16x32_bf16(af[mt][1], b1, acc[mt][nt], 0, 0, 0);
        }
    }
#pragma unroll
    for (int nt = 0; nt < 5; ++nt) {
        int p = nt * 16 + m;
        if (p < 75) {
            int t = p / 25, vp = p - t * 25;
            int base = t * 6656 + vp;
#pragma unroll
            for (int mt = 0; mt < 3; ++mt) {
#pragma unroll
                for (int r = 0; r < 4; ++r) {
                    int R = wave * 48 + mt * 16 + q * 4 + r;
                    int i = R >> 6, o = R & 63;
                    us[base + o * 104 + i * 32] = f2bf(acc[mt][nt][r]);
                }
            }
        }
    }
    __syncthreads();

    short8 bfr[3][2];
#pragma unroll
    for (int i = 0; i < 3; ++i)
#pragma unroll
        for (int nt = 0; nt < 2; ++nt)
            bfr[i][nt] = *(const short8*)(Aib + (i * 32 + nt * 16 + m) * 40 + q * 8);

    float sr[4] = {0.f, 0.f, 0.f, 0.f}, s2r[4] = {0.f, 0.f, 0.f, 0.f};
    float* yb = out + n * CTV_ + t0 * 25;
#pragma unroll
    for (int t = 0; t < 3; ++t) {
        f32x4 a2[2];
        a2[0] = (f32x4)(0.f);
        a2[1] = (f32x4)(0.f);
#pragma unroll
        for (int i = 0; i < 3; ++i) {
            short8 ua = *(const short8*)(us + t * 6656 + (wave * 16 + m) * 104 + i * 32 + q * 8);
            a2[0] = __builtin_amdgcn_mfma_f32_16x16x32_bf16(ua, bfr[i][0], a2[0], 0, 0, 0);
            a2[1] = __builtin_amdgcn_mfma_f32_16x16x32_bf16(ua, bfr[i][1], a2[1], 0, 0, 0);
        }
#pragma unroll
        for (int nt = 0; nt < 2; ++nt) {
            int v = nt * 16 + m;
            if (v < 25) {
#pragma unroll
                for (int r = 0; r < 4; ++r) {
                    int o = wave * 16 + q * 4 + r;
                    float val = a2[nt][r] + db4[r];
                    yb[o * TV_ + t * 25 + v] = val;
                    sr[r] += val;
                    s2r[r] += val * val;
                }
            }
        }
    }

    int bid = blockIdx.y * 100 + blockIdx.x;
#pragma unroll
    for (int r = 0; r < 4; ++r) {
        float s = sr[r], s2 = s2r[r];
#pragma unroll
        for (int d = 1; d < 16; d <<= 1) {
            s += __shfl_xor(s, d, 64);
            s2 += __shfl_xor(s2, d, 64);
        }
        if (m == 0) {
            int o = wave * 16 + q * 4 + r;
            partials[o * NB_ + bid] = s;
            partials[(64 + o) * NB_ + bid] = s2;
        }
    }
}

// ---------------- BN stats: sum partials ----------------
__global__ __launch_bounds__(256) void bn_stats(const float* __restrict__ partials,
                                                float* __restrict__ stats) {
    int j = blockIdx.x;
    int tid = threadIdx.x;
    float s = 0.f;
    for (int idx = tid; idx < NB_; idx += 256) s += partials[j * NB_ + idx];
    for (int d = 32; d > 0; d >>= 1) s += __shfl_down(s, d, 64);
    __shared__ float ls[4];
    if ((tid & 63) == 0) ls[tid >> 6] = s;
    __syncthreads();
    if (tid == 0) stats[j] = ls[0] + ls[1] + ls[2] + ls[3];
}

// ---------------- BN apply + residual + relu, float4 (TV_ % 4 == 0) ----------------
__global__ __launch_bounds__(256) void bn_final4(
    const float* __restrict__ x, const float* __restrict__ stats,
    const float* __restrict__ bnw, const float* __restrict__ bnb,
    float* __restrict__ y) {
    int idx = blockIdx.x * 256 + threadIdx.x;   // 7,680,000 float4s
    int o = (idx / 1875) & 63;                  // TV_/4 = 1875
    const float cnt = (float)(N_ * TV_);
    float mu = stats[o] / cnt;
    float var = stats[64 + o] / cnt - mu * mu;
    float inv = rsqrtf(var + 1e-5f);
    float w = bnw[o], b = bnb[o];
    f32x4 yv = ((const f32x4*)y)[idx];
    f32x4 xv = ((const f32x4*)x)[idx];
    f32x4 r;
#pragma unroll
    for (int k = 0; k < 4; ++k) r[k] = fmaxf((yv[k] - mu) * inv * w + b + xv[k], 0.f);
    ((f32x4*)y)[idx] = r;
}

extern "C" void kernel_launch(void* const* d_in, const int* in_sizes, int n_in,
                              void* d_out, int out_size, void* d_ws, size_t ws_size,
                              hipStream_t stream) {
    (void)in_sizes; (void)n_in; (void)out_size; (void)ws_size;
    const float* x     = (const float*)d_in[0];
    const float* wts   = (const float*)d_in[1];
    const float* A     = (const float*)d_in[2];
    const float* a_w   = (const float*)d_in[3];
    const float* a_b   = (const float*)d_in[4];
    const float* b_w   = (const float*)d_in[5];
    const float* b_b   = (const float*)d_in[6];
    const float* d_wp  = (const float*)d_in[7];
    const float* d_bp  = (const float*)d_in[8];
    const float* t1_w  = (const float*)d_in[9];
    const float* t1_b  = (const float*)d_in[10];
    const float* t2_w  = (const float*)d_in[11];
    const float* t2_b  = (const float*)d_in[12];
    const float* st11_w1 = (const float*)d_in[13];
    const float* st11_w9 = (const float*)d_in[14];
    const float* st11_b  = (const float*)d_in[15];
    const float* st12_w1 = (const float*)d_in[16];
    const float* st12_w9 = (const float*)d_in[17];
    const float* st12_b  = (const float*)d_in[18];
    const float* bn_w  = (const float*)d_in[19];
    const float* bn_b  = (const float*)d_in[20];
    float* out = (float*)d_out;

    // ---- workspace layout (disjoint) ----
    // amix      [0         , 7,500)
    // stats     [8,192     , 8,704)
    // db_sum    [12,288    , 12,544)
    // S         [16,384    , 1,456,384)     9 slabs x 160,000 B
    // dwpk      [1,460,224 , 1,484,800)
    // bpk       [1,486,848 , 1,488,000)     9 x 32 f32 biases
    // wpk_all   [1,490,944 , 1,822,720)     9 x 18432 bf16
    // Gpart     [2,097,152 , 45,297,152)    bf16 [9][60][64][625]
    // partials  [46,137,344, 49,414,144)    128 x 6400 f32
    char* ws = (char*)d_ws;
    float* amix     = (float*)(ws);
    float* stats    = (float*)(ws + 8192);
    float* db_sum   = (float*)(ws + 12288);
    float* S        = (float*)(ws + 16384);
    short* dwpk     = (short*)(ws + 1460224);
    float* bpk      = (float*)(ws + 1486848);
    short* wpk_all  = (short*)(ws + 1490944);
    short* Gpart    = (short*)(ws + 2097152);
    float* partials = (float*)(ws + 46137344);

    amix_kernel<<<1, 128, 0, stream>>>(A, wts, amix);
    dwprep<<<48, 256, 0, stream>>>(d_wp, d_bp, dwpk, db_sum);
    wprep_all<<<650, 256, 0, stream>>>(a_w, b_w, t1_w, t2_w, st11_w1, st12_w1,
                                       st11_w9, st12_w9, a_b, b_b, t1_b, t2_b,
                                       st11_b, st12_b, wpk_all, bpk);
    convgram<<<dim3(60, 64), 256, 0, stream>>>(x, wpk_all, bpk, Gpart);
    gram_finalize_all<<<dim3(64, 9), 256, 0, stream>>>(Gpart, S);
    mega<<<dim3(100, 64), 256, 0, stream>>>(x, amix, S, wts, dwpk, db_sum, out, partials);
    bn_stats<<<128, 256, 0, stream>>>(partials, stats);
    bn_final4<<<30000, 256, 0, stream>>>(x, stats, bn_w, bn_b, out);
}

// Round 3
// 711.375 us; speedup vs baseline: 2.9113x; 1.3628x over previous
//
#include <hip/hip_runtime.h>

#define N_    64
#define C_    64
#define T_    300
#define V_    25
#define IC_   16
#define TV_   7500      // T*V
#define CTV_  480000    // C*T*V  (per-n x slice)
#define NB_   6400      // mega grid blocks (100 x 64)

typedef __attribute__((ext_vector_type(8))) short short8;
typedef __attribute__((ext_vector_type(4))) float f32x4;

static __device__ inline short f2bf(float f) {
    unsigned u = __float_as_uint(f);
    unsigned r = (u + 0x7fff + ((u >> 16) & 1)) >> 16;
    return (short)r;
}
static __device__ inline float bf2f(short s) {
    return __uint_as_float(((unsigned)(unsigned short)s) << 16);
}

// ---------------- A_mix: Chebyshev mix + column softmax ----------------
__global__ void amix_kernel(const float* __restrict__ A, const float* __restrict__ w,
                            float* __restrict__ amix) {
    int tid = threadIdx.x;
    if (tid >= 75) return;
    int s = tid / 25, col = tid % 25;
    const float* As = A + s * 625;
    float av[25], ch4[25];
#pragma unroll
    for (int r = 0; r < 25; ++r) {
        float a = As[r * 25 + col];
        float a2 = a * a;
        float eye = (r == col) ? 1.f : 0.f;
        av[r] = a;
        ch4[r] = 8.f * a2 * a2 - 8.f * a2 + eye;
    }
    float m = -1e30f;
#pragma unroll
    for (int r = 0; r < 25; ++r) m = fmaxf(m, ch4[r] * (1.f / 25.f));
    float e[25];
    float sum = 0.f;
#pragma unroll
    for (int r = 0; r < 25; ++r) { e[r] = __expf(ch4[r] * (1.f / 25.f) - m); sum += e[r]; }
    float inv = 1.f / sum;
    float w0 = w[0], w1 = w[1], w2 = w[2], w3 = w[3], w4 = w[4];
#pragma unroll
    for (int r = 0; r < 25; ++r) {
        float a = av[r], a2 = a * a;
        float eye = (r == col) ? 1.f : 0.f;
        amix[s * 625 + r * 25 + col] =
            w0 * a + w1 * (e[r] * inv) + w2 * ch4[r] +
            w3 * (4.f * a2 * a - 3.f * a) + w4 * (2.f * a2 - eye);
    }
}

// ---------------- weight prep, ALL 9 pairs in one launch ----------------
__global__ void wprep_all(
    const float* __restrict__ a_w, const float* __restrict__ b_w,
    const float* __restrict__ t1_w, const float* __restrict__ t2_w,
    const float* __restrict__ st11_w1, const float* __restrict__ st12_w1,
    const float* __restrict__ st11_w9, const float* __restrict__ st12_w9,
    const float* __restrict__ a_b, const float* __restrict__ b_b,
    const float* __restrict__ t1_b, const float* __restrict__ t2_b,
    const float* __restrict__ st11_b, const float* __restrict__ st12_b,
    short* __restrict__ wpk_all, float* __restrict__ bpk) {
    int idx = blockIdx.x * 256 + threadIdx.x;
    int pair, r;
    bool bias_path = false;
    if (idx < 9 * 18432) {
        pair = idx / 18432; r = idx - pair * 18432;
    } else if (idx < 9 * 18432 + 288) {
        bias_path = true;
        int bidx = idx - 9 * 18432;
        pair = bidx >> 5; r = bidx & 31;
    } else return;

    const float *w1, *w2, *bb1, *bb2; int taps;
    switch (pair) {
        case 0: taps=1; w1=a_w;          w2=b_w;          bb1=a_b;       bb2=b_b;       break;
        case 1: taps=9; w1=t1_w;         w2=t2_w;         bb1=t1_b;      bb2=t2_b;      break;
        case 2: taps=1; w1=st11_w1;      w2=st12_w1;      bb1=st11_b;    bb2=st12_b;    break;
        case 3: taps=1; w1=a_w+1024;     w2=b_w+1024;     bb1=a_b+16;    bb2=b_b+16;    break;
        case 4: taps=9; w1=t1_w+9216;    w2=t2_w+9216;    bb1=t1_b+16;   bb2=t2_b+16;   break;
        case 5: taps=9; w1=st11_w9;      w2=st12_w9;      bb1=st11_b+16; bb2=st12_b+16; break;
        case 6: taps=1; w1=a_w+2048;     w2=b_w+2048;     bb1=a_b+32;    bb2=b_b+32;    break;
        case 7: taps=9; w1=t1_w+18432;   w2=t2_w+18432;   bb1=t1_b+32;   bb2=t2_b+32;   break;
        default: taps=1; w1=st11_w1+1024; w2=st12_w1+1024; bb1=st11_b+32; bb2=st12_b+32; break;
    }
    if (bias_path) {
        int half = r >> 4, o = r & 15;
        bpk[pair * 32 + r] = half ? bb2[o] : bb1[o];
        return;
    }
    if (r >= taps * 2048) return;
    int j = r & 7;
    int l = (r >> 3) & 63;
    int half = (r >> 9) & 1;
    int kk = r >> 10;
    int K = kk * 32 + ((l >> 4) << 3) + j;
    int c = K & 63, k = K >> 6;
    int o = l & 15;
    const float* w = half ? w2 : w1;
    wpk_all[pair * 18432 + r] = f2bf(w[(o * 64 + c) * taps + k]);
}

// ---------------- dw prep: 12 m-tiles, K = c (64), bf16 A-frags ----------------
__global__ void dwprep(const float* __restrict__ dw, const float* __restrict__ db,
                       short* __restrict__ dwpk, float* __restrict__ db_sum) {
    int idx = blockIdx.x * 256 + threadIdx.x;
    if (idx < 12288) {
        int j = idx & 7;
        int lane = (idx >> 3) & 63;
        int kk = (idx >> 9) & 1;
        int mt = idx >> 10;
        int R = mt * 16 + (lane & 15);
        int c = kk * 32 + ((lane >> 4) << 3) + j;
        int i = R >> 6, o = R & 63;
        dwpk[idx] = f2bf(dw[i * 4096 + o * 64 + c]);
    }
    if (idx < 64) db_sum[idx] = db[idx] + db[64 + idx] + db[128 + idx];
}

// ---------------- per-pair epilogue: fT dbuf write -> barrier -> gram -> Gpart ----------------
static __device__ __attribute__((always_inline)) void pair_epilogue(
    f32x4 acc[2][2], int pair, int buf, short* fTb, const float* __restrict__ bpk,
    short* __restrict__ Gpart, int n, int ch, int wave, int lane) {
    int q = lane >> 4, m = lane & 15;
    int pw = wave * 32;
    int mt = wave >> 1, ntl = wave & 1;
    short* fb = fTb + buf * 6656;
    f32x4 bh0 = *(const f32x4*)(bpk + pair * 32 + q * 4);
    f32x4 bh1 = *(const f32x4*)(bpk + pair * 32 + 16 + q * 4);
#pragma unroll
    for (int h = 0; h < 2; ++h) {
#pragma unroll
        for (int nt = 0; nt < 2; ++nt) {
            int p = pw + nt * 16 + m;
            if (p < 125) {
                int tl = p / 25, v = p - tl * 25;
#pragma unroll
                for (int r = 0; r < 4; ++r) {
                    float bv = h ? bh1[r] : bh0[r];
                    fb[h * 3328 + v * 104 + tl * 16 + q * 4 + r] = f2bf(acc[h][nt][r] + bv);
                }
            }
        }
    }
    __syncthreads();   // fb ready; prior pair's gram used the other buffer

    f32x4 g = (f32x4)(0.f);
#pragma unroll
    for (int s = 0; s < 3; ++s) {
        short8 af = *(const short8*)(fb + (mt * 16 + m) * 104 + s * 32 + q * 8);
        short8 bf = *(const short8*)(fb + 3328 + (ntl * 16 + m) * 104 + s * 32 + q * 8);
        g = __builtin_amdgcn_mfma_f32_16x16x32_bf16(af, bf, g, 0, 0, 0);
    }
    int gvp = ntl * 16 + m;
    if (gvp < 25) {
        // layout: [pair][n][ch][625]  (coalesced finalize reads)
        short* gdst = Gpart + ((pair * 64 + n) * 60 + ch) * 625 + gvp;
#pragma unroll
        for (int r = 0; r < 4; ++r) {
            int v = mt * 16 + q * 4 + r;
            if (v < 25) gdst[v * 25] = f2bf(g[r]);
        }
    }
}

// ---------------- fused conv + gram: all 9 pairs, two reg-phases, batched staging ----------------
__global__ __launch_bounds__(256, 2) void convgram(
    const float* __restrict__ x, const short* __restrict__ wpk_all,
    const float* __restrict__ bpk, short* __restrict__ Gpart) {
    __shared__ __align__(16) short xs[328 * 72];      // 47,232 B
    __shared__ __align__(16) short fTb[2 * 6656];     // 26,624 B dbuf
    int tid = threadIdx.x;
    int n = blockIdx.y, ch = blockIdx.x;
    int p0 = blockIdx.x * 125;
    const float* xn = x + n * CTV_;

    // batched staging: 82 elements/thread, groups of 8 (8 loads in flight -> 1 wait)
    {
        float vb[8]; int ib[8];
        for (int g = 0; g < 10; ++g) {
#pragma unroll
            for (int u = 0; u < 8; ++u) {
                int jj = tid + (g * 8 + u) * 256;
                int c = jj / 328, rr = jj - c * 328;
                int pp = p0 - 100 + rr;
                vb[u] = (pp >= 0 && pp < TV_) ? xn[c * TV_ + pp] : 0.f;
                ib[u] = rr * 72 + c;
            }
#pragma unroll
            for (int u = 0; u < 8; ++u) xs[ib[u]] = f2bf(vb[u]);
        }
#pragma unroll
        for (int u = 0; u < 2; ++u) {
            int jj = tid + (80 + u) * 256;
            int c = jj / 328, rr = jj - c * 328;
            int pp = p0 - 100 + rr;
            xs[rr * 72 + c] = f2bf((pp >= 0 && pp < TV_) ? xn[c * TV_ + pp] : 0.f);
        }
    }
    for (int jj = tid; jj < 6656; jj += 256) ((int*)fTb)[jj] = 0;
    __syncthreads();

    int wave = tid >> 6, lane = tid & 63, q = lane >> 4, m = lane & 15;
    int pw = wave * 32;

    // ---- phase 1: one-tap pairs {0,2,3,6,8}, acc5 = 80 regs ----
    {
        constexpr int OP[5] = {0, 2, 3, 6, 8};
        f32x4 acc5[5][2][2];
#pragma unroll
        for (int p = 0; p < 5; ++p)
#pragma unroll
            for (int h = 0; h < 2; ++h)
#pragma unroll
                for (int nt = 0; nt < 2; ++nt) acc5[p][h][nt] = (f32x4)(0.f);
#pragma unroll
        for (int kc2 = 0; kc2 < 2; ++kc2) {
            int c0 = kc2 * 32;
            short8 b0 = *(const short8*)(xs + (pw + m + 100) * 72 + c0 + q * 8);
            short8 b1 = *(const short8*)(xs + (pw + m + 116) * 72 + c0 + q * 8);
#pragma unroll
            for (int pi = 0; pi < 5; ++pi) {
                const short* wp = wpk_all + OP[pi] * 18432 + kc2 * 1024 + lane * 8;
                short8 a0 = *(const short8*)(wp);
                short8 a1 = *(const short8*)(wp + 512);
                acc5[pi][0][0] = __builtin_amdgcn_mfma_f32_16x16x32_bf16(a0, b0, acc5[pi][0][0], 0, 0, 0);
                acc5[pi][0][1] = __builtin_amdgcn_mfma_f32_16x16x32_bf16(a0, b1, acc5[pi][0][1], 0, 0, 0);
                acc5[pi][1][0] = __builtin_amdgcn_mfma_f32_16x16x32_bf16(a1, b0, acc5[pi][1][0], 0, 0, 0);
                acc5[pi][1][1] = __builtin_amdgcn_mfma_f32_16x16x32_bf16(a1, b1, acc5[pi][1][1], 0, 0, 0);
            }
        }
#pragma unroll
        for (int pi = 0; pi < 5; ++pi)
            pair_epilogue(acc5[pi], OP[pi], pi & 1, fTb, bpk, Gpart, n, ch, wave, lane);
    }

    // ---- phase 2: nine-tap pairs {1,4,5,7}, acc4 = 64 regs ----
    {
        constexpr int NP[4] = {1, 4, 5, 7};
        f32x4 acc4[4][2][2];
#pragma unroll
        for (int p = 0; p < 4; ++p)
#pragma unroll
            for (int h = 0; h < 2; ++h)
#pragma unroll
                for (int nt = 0; nt < 2; ++nt) acc4[p][h][nt] = (f32x4)(0.f);
#pragma unroll
        for (int kc = 0; kc < 18; ++kc) {
            int k = kc >> 1;
            int c0 = (kc & 1) * 32;
            short8 b0 = *(const short8*)(xs + (pw + m + 25 * k) * 72 + c0 + q * 8);
            short8 b1 = *(const short8*)(xs + (pw + m + 25 * k + 16) * 72 + c0 + q * 8);
#pragma unroll
            for (int pi = 0; pi < 4; ++pi) {
                const short* wp = wpk_all + NP[pi] * 18432 + kc * 1024 + lane * 8;
                short8 a0 = *(const short8*)(wp);
                short8 a1 = *(const short8*)(wp + 512);
                acc4[pi][0][0] = __builtin_amdgcn_mfma_f32_16x16x32_bf16(a0, b0, acc4[pi][0][0], 0, 0, 0);
                acc4[pi][0][1] = __builtin_amdgcn_mfma_f32_16x16x32_bf16(a0, b1, acc4[pi][0][1], 0, 0, 0);
                acc4[pi][1][0] = __builtin_amdgcn_mfma_f32_16x16x32_bf16(a1, b0, acc4[pi][1][0], 0, 0, 0);
                acc4[pi][1][1] = __builtin_amdgcn_mfma_f32_16x16x32_bf16(a1, b1, acc4[pi][1][1], 0, 0, 0);
            }
        }
#pragma unroll
        for (int pi = 0; pi < 4; ++pi)
            pair_epilogue(acc4[pi], NP[pi], (5 + pi) & 1, fTb, bpk, Gpart, n, ch, wave, lane);
    }
}

// ---------------- gram finalize: coalesced unrolled sum + column softmax ----------------
__global__ __launch_bounds__(256) void gram_finalize_all(
    const short* __restrict__ Gpart, float* __restrict__ S) {
    __shared__ float sm[625];
    int n = blockIdx.x, pair = blockIdx.y;
    int tid = threadIdx.x;
    const short* g = Gpart + (pair * 64 + n) * 60 * 625;
    for (int qq = tid; qq < 625; qq += 256) {
        float s = 0.f;
#pragma unroll
        for (int ch = 0; ch < 60; ++ch) s += bf2f(g[ch * 625 + qq]);
        sm[qq] = s * (1.f / 4800.f);
    }
    __syncthreads();
    if (tid < 25) {
        int col = tid;
        float m = -1e30f;
#pragma unroll
        for (int r = 0; r < 25; ++r) m = fmaxf(m, sm[r * 25 + col]);
        float e[25];
        float sum = 0.f;
#pragma unroll
        for (int r = 0; r < 25; ++r) { e[r] = __expf(sm[r * 25 + col] - m); sum += e[r]; }
        float inv = 1.f / sum;
#pragma unroll
        for (int r = 0; r < 25; ++r)
            S[pair * 40000 + n * 625 + r * 25 + col] = e[r] * inv;
    }
}

// ---------------- mega: y = sum_i (dw_i @ x) @ Ai, all subsets, + BN partials ----------------
__global__ __launch_bounds__(256) void mega(
    const float* __restrict__ x, const float* __restrict__ amix,
    const float* __restrict__ S, const float* __restrict__ wts,
    const short* __restrict__ dwpk, const float* __restrict__ db_sum,
    float* __restrict__ out, float* __restrict__ partials) {
    __shared__ __align__(16) short xs[80 * 72];       // [p][c] bf16, stride 72
    __shared__ __align__(16) short us[3 * 64 * 104];  // [t][o][K=96 pad 104] bf16
    __shared__ __align__(16) short Aib[3 * 32 * 40];  // [i][v][vp pad 40] bf16

    int tid = threadIdx.x;
    int n = blockIdx.y;
    int t0 = blockIdx.x * 3;
    const float* xn = x + n * CTV_ + t0 * 25;

    // batched staging: 20 elems/thread, 2 groups of 10
    {
        float vb[10]; int ib[10];
        for (int g = 0; g < 2; ++g) {
#pragma unroll
            for (int u = 0; u < 10; ++u) {
                int jj = tid + (g * 10 + u) * 256;
                int c = jj / 80, p = jj - c * 80;
                vb[u] = (p < 75) ? xn[c * TV_ + p] : 0.f;
                ib[u] = p * 72 + c;
            }
#pragma unroll
            for (int u = 0; u < 10; ++u) xs[ib[u]] = f2bf(vb[u]);
        }
    }
    for (int jj = tid; jj < 3 * 64 * 52; jj += 256) ((int*)us)[jj] = 0;
    float w5 = wts[5], w6 = wts[6], w7 = wts[7];
#pragma unroll
    for (int it = 0; it < 15; ++it) {
        int jj = tid + it * 256;
        int i = jj / 1280;
        int rem = jj - i * 1280;
        int v = rem / 40, vp = rem - v * 40;
        float val = 0.f;
        if (v < 25 && vp < 25) {
            int e = vp * 25 + v;
            val = amix[i * 625 + e]
                + w5 * S[(i * 3 + 0) * 40000 + n * 625 + e]
                + w6 * S[(i * 3 + 1) * 40000 + n * 625 + e]
                + w7 * S[(i * 3 + 2) * 40000 + n * 625 + e];
        }
        Aib[jj] = f2bf(val);
    }

    int wave = tid >> 6, lane = tid & 63;
    int q = lane >> 4, m = lane & 15;

    short8 af[3][2];
#pragma unroll
    for (int mt = 0; mt < 3; ++mt)
#pragma unroll
        for (int kk = 0; kk < 2; ++kk)
            af[mt][kk] = *(const short8*)(dwpk + ((wave * 3 + mt) * 2 + kk) * 512 + lane * 8);
    float db4[4];
#pragma unroll
    for (int r = 0; r < 4; ++r) db4[r] = db_sum[wave * 16 + q * 4 + r];

    __syncthreads();

    f32x4 acc[3][5];
#pragma unroll
    for (int mt = 0; mt < 3; ++mt)
#pragma unroll
        for (int nt = 0; nt < 5; ++nt) acc[mt][nt] = (f32x4)(0.f);

#pragma unroll
    for (int nt = 0; nt < 5; ++nt) {
        short8 b0 = *(const short8*)(xs + (nt * 16 + m) * 72 + q * 8);
        short8 b1 = *(const short8*)(xs + (nt * 16 + m) * 72 + 32 + q * 8);
#pragma unroll
        for (int mt = 0; mt < 3; ++mt) {
            acc[mt][nt] = __builtin_amdgcn_mfma_f32_16x16x32_bf16(af[mt][0], b0, acc[mt][nt], 0, 0, 0);
            acc[mt][nt] = __builtin_amdgcn_mfma_f32_16x16x32_bf16(af[mt][1], b1, acc[mt][nt], 0, 0, 0);
        }
    }
#pragma unroll
    for (int nt = 0; nt < 5; ++nt) {
        int p = nt * 16 + m;
        if (p < 75) {
            int t = p / 25, vp = p - t * 25;
            int base = t * 6656 + vp;
#pragma unroll
            for (int mt = 0; mt < 3; ++mt) {
#pragma unroll
                for (int r = 0; r < 4; ++r) {
                    int R = wave * 48 + mt * 16 + q * 4 + r;
                    int i = R >> 6, o = R & 63;
                    us[base + o * 104 + i * 32] = f2bf(acc[mt][nt][r]);
                }
            }
        }
    }
    __syncthreads();

    short8 bfr[3][2];
#pragma unroll
    for (int i = 0; i < 3; ++i)
#pragma unroll
        for (int nt = 0; nt < 2; ++nt)
            bfr[i][nt] = *(const short8*)(Aib + (i * 32 + nt * 16 + m) * 40 + q * 8);

    float sr[4] = {0.f, 0.f, 0.f, 0.f}, s2r[4] = {0.f, 0.f, 0.f, 0.f};
    float* yb = out + n * CTV_ + t0 * 25;
#pragma unroll
    for (int t = 0; t < 3; ++t) {
        f32x4 a2[2];
        a2[0] = (f32x4)(0.f);
        a2[1] = (f32x4)(0.f);
#pragma unroll
        for (int i = 0; i < 3; ++i) {
            short8 ua = *(const short8*)(us + t * 6656 + (wave * 16 + m) * 104 + i * 32 + q * 8);
            a2[0] = __builtin_amdgcn_mfma_f32_16x16x32_bf16(ua, bfr[i][0], a2[0], 0, 0, 0);
            a2[1] = __builtin_amdgcn_mfma_f32_16x16x32_bf16(ua, bfr[i][1], a2[1], 0, 0, 0);
        }
#pragma unroll
        for (int nt = 0; nt < 2; ++nt) {
            int v = nt * 16 + m;
            if (v < 25) {
#pragma unroll
                for (int r = 0; r < 4; ++r) {
                    int o = wave * 16 + q * 4 + r;
                    float val = a2[nt][r] + db4[r];
                    yb[o * TV_ + t * 25 + v] = val;
                    sr[r] += val;
                    s2r[r] += val * val;
                }
            }
        }
    }

    int bid = blockIdx.y * 100 + blockIdx.x;
#pragma unroll
    for (int r = 0; r < 4; ++r) {
        float s = sr[r], s2 = s2r[r];
#pragma unroll
        for (int d = 1; d < 16; d <<= 1) {
            s += __shfl_xor(s, d, 64);
            s2 += __shfl_xor(s2, d, 64);
        }
        if (m == 0) {
            int o = wave * 16 + q * 4 + r;
            partials[o * NB_ + bid] = s;
            partials[(64 + o) * NB_ + bid] = s2;
        }
    }
}

// ---------------- BN stats: sum partials ----------------
__global__ __launch_bounds__(256) void bn_stats(const float* __restrict__ partials,
                                                float* __restrict__ stats) {
    int j = blockIdx.x;
    int tid = threadIdx.x;
    float s = 0.f;
    for (int idx = tid; idx < NB_; idx += 256) s += partials[j * NB_ + idx];
    for (int d = 32; d > 0; d >>= 1) s += __shfl_down(s, d, 64);
    __shared__ float ls[4];
    if ((tid & 63) == 0) ls[tid >> 6] = s;
    __syncthreads();
    if (tid == 0) stats[j] = ls[0] + ls[1] + ls[2] + ls[3];
}

// ---------------- BN apply + residual + relu, float4 (TV_ % 4 == 0) ----------------
__global__ __launch_bounds__(256) void bn_final4(
    const float* __restrict__ x, const float* __restrict__ stats,
    const float* __restrict__ bnw, const float* __restrict__ bnb,
    float* __restrict__ y) {
    int idx = blockIdx.x * 256 + threadIdx.x;   // 7,680,000 float4s
    int o = (idx / 1875) & 63;                  // TV_/4 = 1875
    const float cnt = (float)(N_ * TV_);
    float mu = stats[o] / cnt;
    float var = stats[64 + o] / cnt - mu * mu;
    float inv = rsqrtf(var + 1e-5f);
    float w = bnw[o], b = bnb[o];
    f32x4 yv = ((const f32x4*)y)[idx];
    f32x4 xv = ((const f32x4*)x)[idx];
    f32x4 r;
#pragma unroll
    for (int k = 0; k < 4; ++k) r[k] = fmaxf((yv[k] - mu) * inv * w + b + xv[k], 0.f);
    ((f32x4*)y)[idx] = r;
}

extern "C" void kernel_launch(void* const* d_in, const int* in_sizes, int n_in,
                              void* d_out, int out_size, void* d_ws, size_t ws_size,
                              hipStream_t stream) {
    (void)in_sizes; (void)n_in; (void)out_size; (void)ws_size;
    const float* x     = (const float*)d_in[0];
    const float* wts   = (const float*)d_in[1];
    const float* A     = (const float*)d_in[2];
    const float* a_w   = (const float*)d_in[3];
    const float* a_b   = (const float*)d_in[4];
    const float* b_w   = (const float*)d_in[5];
    const float* b_b   = (const float*)d_in[6];
    const float* d_wp  = (const float*)d_in[7];
    const float* d_bp  = (const float*)d_in[8];
    const float* t1_w  = (const float*)d_in[9];
    const float* t1_b  = (const float*)d_in[10];
    const float* t2_w  = (const float*)d_in[11];
    const float* t2_b  = (const float*)d_in[12];
    const float* st11_w1 = (const float*)d_in[13];
    const float* st11_w9 = (const float*)d_in[14];
    const float* st11_b  = (const float*)d_in[15];
    const float* st12_w1 = (const float*)d_in[16];
    const float* st12_w9 = (const float*)d_in[17];
    const float* st12_b  = (const float*)d_in[18];
    const float* bn_w  = (const float*)d_in[19];
    const float* bn_b  = (const float*)d_in[20];
    float* out = (float*)d_out;

    // ---- workspace layout (disjoint) ----
    // amix      [0         , 7,500)
    // stats     [8,192     , 8,704)
    // db_sum    [12,288    , 12,544)
    // S         [16,384    , 1,456,384)     9 slabs x 160,000 B
    // dwpk      [1,460,224 , 1,484,800)
    // bpk       [1,486,848 , 1,488,000)     9 x 32 f32 biases
    // wpk_all   [1,490,944 , 1,822,720)     9 x 18432 bf16
    // Gpart     [2,097,152 , 45,297,152)    bf16 [9][64][60][625]
    // partials  [46,137,344, 49,414,144)    128 x 6400 f32
    char* ws = (char*)d_ws;
    float* amix     = (float*)(ws);
    float* stats    = (float*)(ws + 8192);
    float* db_sum   = (float*)(ws + 12288);
    float* S        = (float*)(ws + 16384);
    short* dwpk     = (short*)(ws + 1460224);
    float* bpk      = (float*)(ws + 1486848);
    short* wpk_all  = (short*)(ws + 1490944);
    short* Gpart    = (short*)(ws + 2097152);
    float* partials = (float*)(ws + 46137344);

    amix_kernel<<<1, 128, 0, stream>>>(A, wts, amix);
    dwprep<<<48, 256, 0, stream>>>(d_wp, d_bp, dwpk, db_sum);
    wprep_all<<<650, 256, 0, stream>>>(a_w, b_w, t1_w, t2_w, st11_w1, st12_w1,
                                       st11_w9, st12_w9, a_b, b_b, t1_b, t2_b,
                                       st11_b, st12_b, wpk_all, bpk);
    convgram<<<dim3(60, 64), 256, 0, stream>>>(x, wpk_all, bpk, Gpart);
    gram_finalize_all<<<dim3(64, 9), 256, 0, stream>>>(Gpart, S);
    mega<<<dim3(100, 64), 256, 0, stream>>>(x, amix, S, wts, dwpk, db_sum, out, partials);
    bn_stats<<<128, 256, 0, stream>>>(partials, stats);
    bn_final4<<<30000, 256, 0, stream>>>(x, stats, bn_w, bn_b, out);
}

// Round 4
// 536.705 us; speedup vs baseline: 3.8588x; 1.3255x over previous
//
#include <hip/hip_runtime.h>

#define N_    64
#define C_    64
#define T_    300
#define V_    25
#define IC_   16
#define TV_   7500      // T*V
#define CTV_  480000    // C*T*V  (per-n x slice)
#define NB_   6400      // mega grid blocks (100 x 64)

typedef __attribute__((ext_vector_type(8))) short short8;
typedef __attribute__((ext_vector_type(4))) float f32x4;

static __device__ inline short f2bf(float f) {
    unsigned u = __float_as_uint(f);
    unsigned r = (u + 0x7fff + ((u >> 16) & 1)) >> 16;
    return (short)r;
}
static __device__ inline float bf2f(short s) {
    return __uint_as_float(((unsigned)(unsigned short)s) << 16);
}

// ---------------- A_mix: Chebyshev mix + column softmax ----------------
__global__ void amix_kernel(const float* __restrict__ A, const float* __restrict__ w,
                            float* __restrict__ amix) {
    int tid = threadIdx.x;
    if (tid >= 75) return;
    int s = tid / 25, col = tid % 25;
    const float* As = A + s * 625;
    float av[25], ch4[25];
#pragma unroll
    for (int r = 0; r < 25; ++r) {
        float a = As[r * 25 + col];
        float a2 = a * a;
        float eye = (r == col) ? 1.f : 0.f;
        av[r] = a;
        ch4[r] = 8.f * a2 * a2 - 8.f * a2 + eye;
    }
    float m = -1e30f;
#pragma unroll
    for (int r = 0; r < 25; ++r) m = fmaxf(m, ch4[r] * (1.f / 25.f));
    float e[25];
    float sum = 0.f;
#pragma unroll
    for (int r = 0; r < 25; ++r) { e[r] = __expf(ch4[r] * (1.f / 25.f) - m); sum += e[r]; }
    float inv = 1.f / sum;
    float w0 = w[0], w1 = w[1], w2 = w[2], w3 = w[3], w4 = w[4];
#pragma unroll
    for (int r = 0; r < 25; ++r) {
        float a = av[r], a2 = a * a;
        float eye = (r == col) ? 1.f : 0.f;
        amix[s * 625 + r * 25 + col] =
            w0 * a + w1 * (e[r] * inv) + w2 * ch4[r] +
            w3 * (4.f * a2 * a - 3.f * a) + w4 * (2.f * a2 - eye);
    }
}

// ---------------- weight prep, ALL 9 pairs in one launch ----------------
__global__ void wprep_all(
    const float* __restrict__ a_w, const float* __restrict__ b_w,
    const float* __restrict__ t1_w, const float* __restrict__ t2_w,
    const float* __restrict__ st11_w1, const float* __restrict__ st12_w1,
    const float* __restrict__ st11_w9, const float* __restrict__ st12_w9,
    const float* __restrict__ a_b, const float* __restrict__ b_b,
    const float* __restrict__ t1_b, const float* __restrict__ t2_b,
    const float* __restrict__ st11_b, const float* __restrict__ st12_b,
    short* __restrict__ wpk_all, float* __restrict__ bpk) {
    int idx = blockIdx.x * 256 + threadIdx.x;
    int pair, r;
    bool bias_path = false;
    if (idx < 9 * 18432) {
        pair = idx / 18432; r = idx - pair * 18432;
    } else if (idx < 9 * 18432 + 288) {
        bias_path = true;
        int bidx = idx - 9 * 18432;
        pair = bidx >> 5; r = bidx & 31;
    } else return;

    const float *w1, *w2, *bb1, *bb2; int taps;
    switch (pair) {
        case 0: taps=1; w1=a_w;          w2=b_w;          bb1=a_b;       bb2=b_b;       break;
        case 1: taps=9; w1=t1_w;         w2=t2_w;         bb1=t1_b;      bb2=t2_b;      break;
        case 2: taps=1; w1=st11_w1;      w2=st12_w1;      bb1=st11_b;    bb2=st12_b;    break;
        case 3: taps=1; w1=a_w+1024;     w2=b_w+1024;     bb1=a_b+16;    bb2=b_b+16;    break;
        case 4: taps=9; w1=t1_w+9216;    w2=t2_w+9216;    bb1=t1_b+16;   bb2=t2_b+16;   break;
        case 5: taps=9; w1=st11_w9;      w2=st12_w9;      bb1=st11_b+16; bb2=st12_b+16; break;
        case 6: taps=1; w1=a_w+2048;     w2=b_w+2048;     bb1=a_b+32;    bb2=b_b+32;    break;
        case 7: taps=9; w1=t1_w+18432;   w2=t2_w+18432;   bb1=t1_b+32;   bb2=t2_b+32;   break;
        default: taps=1; w1=st11_w1+1024; w2=st12_w1+1024; bb1=st11_b+32; bb2=st12_b+32; break;
    }
    if (bias_path) {
        int half = r >> 4, o = r & 15;
        bpk[pair * 32 + r] = half ? bb2[o] : bb1[o];
        return;
    }
    if (r >= taps * 2048) return;
    int j = r & 7;
    int l = (r >> 3) & 63;
    int half = (r >> 9) & 1;
    int kk = r >> 10;
    int K = kk * 32 + ((l >> 4) << 3) + j;
    int c = K & 63, k = K >> 6;
    int o = l & 15;
    const float* w = half ? w2 : w1;
    wpk_all[pair * 18432 + r] = f2bf(w[(o * 64 + c) * taps + k]);
}

// ---------------- dw prep: 12 m-tiles, K = c (64), bf16 A-frags ----------------
__global__ void dwprep(const float* __restrict__ dw, const float* __restrict__ db,
                       short* __restrict__ dwpk, float* __restrict__ db_sum) {
    int idx = blockIdx.x * 256 + threadIdx.x;
    if (idx < 12288) {
        int j = idx & 7;
        int lane = (idx >> 3) & 63;
        int kk = (idx >> 9) & 1;
        int mt = idx >> 10;
        int R = mt * 16 + (lane & 15);
        int c = kk * 32 + ((lane >> 4) << 3) + j;
        int i = R >> 6, o = R & 63;
        dwpk[idx] = f2bf(dw[i * 4096 + o * 64 + c]);
    }
    if (idx < 64) db_sum[idx] = db[idx] + db[64 + idx] + db[128 + idx];
}

// ---------------- conv helpers (per wave-group pair lists) ----------------
template <int CNT>
static __device__ __attribute__((always_inline)) void conv_onetap(
    const int (&PL)[CNT], const short* __restrict__ wpk_all, const short* xs,
    int pw, int lane, f32x4 (*acc)[2][2]) {
    int q = lane >> 4, m = lane & 15;
#pragma unroll
    for (int kc2 = 0; kc2 < 2; ++kc2) {
        int c0 = kc2 * 32;
        short8 b0 = *(const short8*)(xs + (pw + m + 100) * 72 + c0 + q * 8);
        short8 b1 = *(const short8*)(xs + (pw + m + 116) * 72 + c0 + q * 8);
#pragma unroll
        for (int pi = 0; pi < CNT; ++pi) {
            const short* wp = wpk_all + PL[pi] * 18432 + kc2 * 1024 + lane * 8;
            short8 a0 = *(const short8*)(wp);
            short8 a1 = *(const short8*)(wp + 512);
            acc[pi][0][0] = __builtin_amdgcn_mfma_f32_16x16x32_bf16(a0, b0, acc[pi][0][0], 0, 0, 0);
            acc[pi][0][1] = __builtin_amdgcn_mfma_f32_16x16x32_bf16(a0, b1, acc[pi][0][1], 0, 0, 0);
            acc[pi][1][0] = __builtin_amdgcn_mfma_f32_16x16x32_bf16(a1, b0, acc[pi][1][0], 0, 0, 0);
            acc[pi][1][1] = __builtin_amdgcn_mfma_f32_16x16x32_bf16(a1, b1, acc[pi][1][1], 0, 0, 0);
        }
    }
}

template <int CNT>
static __device__ __attribute__((always_inline)) void conv_ninetap(
    const int (&PL)[CNT], const short* __restrict__ wpk_all, const short* xs,
    int pw, int lane, f32x4 (*acc)[2][2]) {
    int q = lane >> 4, m = lane & 15;
#pragma unroll
    for (int kc = 0; kc < 18; ++kc) {
        int k = kc >> 1;
        int c0 = (kc & 1) * 32;
        short8 b0 = *(const short8*)(xs + (pw + m + 25 * k) * 72 + c0 + q * 8);
        short8 b1 = *(const short8*)(xs + (pw + m + 25 * k + 16) * 72 + c0 + q * 8);
#pragma unroll
        for (int pi = 0; pi < CNT; ++pi) {
            const short* wp = wpk_all + PL[pi] * 18432 + kc * 1024 + lane * 8;
            short8 a0 = *(const short8*)(wp);
            short8 a1 = *(const short8*)(wp + 512);
            acc[pi][0][0] = __builtin_amdgcn_mfma_f32_16x16x32_bf16(a0, b0, acc[pi][0][0], 0, 0, 0);
            acc[pi][0][1] = __builtin_amdgcn_mfma_f32_16x16x32_bf16(a0, b1, acc[pi][0][1], 0, 0, 0);
            acc[pi][1][0] = __builtin_amdgcn_mfma_f32_16x16x32_bf16(a1, b0, acc[pi][1][0], 0, 0, 0);
            acc[pi][1][1] = __builtin_amdgcn_mfma_f32_16x16x32_bf16(a1, b1, acc[pi][1][1], 0, 0, 0);
        }
    }
}

// ---------------- epilogue pieces ----------------
static __device__ __attribute__((always_inline)) void fT_write(
    const f32x4 acc[2][2], int pair, short* fb, const float* __restrict__ bpk,
    int wq, int lane) {
    int q = lane >> 4, m = lane & 15;
    int pw = wq * 32;
    f32x4 bh0 = *(const f32x4*)(bpk + pair * 32 + q * 4);
    f32x4 bh1 = *(const f32x4*)(bpk + pair * 32 + 16 + q * 4);
#pragma unroll
    for (int h = 0; h < 2; ++h) {
#pragma unroll
        for (int nt = 0; nt < 2; ++nt) {
            int p = pw + nt * 16 + m;
            if (p < 125) {
                int tl = p / 25, v = p - tl * 25;
#pragma unroll
                for (int r = 0; r < 4; ++r) {
                    float bv = h ? bh1[r] : bh0[r];
                    fb[h * 3328 + v * 104 + tl * 16 + q * 4 + r] = f2bf(acc[h][nt][r] + bv);
                }
            }
        }
    }
}

static __device__ __attribute__((always_inline)) void gram_store(
    const short* fb, int pair, short* __restrict__ Gpart, int n, int ch,
    int wq, int lane) {
    int q = lane >> 4, m = lane & 15;
    int mt = wq >> 1, ntl = wq & 1;
    f32x4 g = (f32x4)(0.f);
#pragma unroll
    for (int s = 0; s < 3; ++s) {
        short8 af = *(const short8*)(fb + (mt * 16 + m) * 104 + s * 32 + q * 8);
        short8 bf = *(const short8*)(fb + 3328 + (ntl * 16 + m) * 104 + s * 32 + q * 8);
        g = __builtin_amdgcn_mfma_f32_16x16x32_bf16(af, bf, g, 0, 0, 0);
    }
    int gvp = ntl * 16 + m;
    if (gvp < 25) {
        // layout: [pair][n][ch][625]
        short* gdst = Gpart + ((pair * 64 + n) * 60 + ch) * 625 + gvp;
#pragma unroll
        for (int r = 0; r < 4; ++r) {
            int v = mt * 16 + q * 4 + r;
            if (v < 25) gdst[v * 25] = f2bf(g[r]);
        }
    }
}

// ---------------- fused conv + gram: 8 waves, pairs split across 2 wave-groups ----------------
// grp0: one-tap {0,2,3} + nine-tap {1,4};  grp1: one-tap {6,8} + nine-tap {5,7}.
// Each group owns one fT buffer; barrier counts equalized across groups.
__global__ __launch_bounds__(512, 4) void convgram(
    const float* __restrict__ x, const short* __restrict__ wpk_all,
    const float* __restrict__ bpk, short* __restrict__ Gpart) {
    __shared__ __align__(16) short xs[328 * 72];      // 47,232 B
    __shared__ __align__(16) short fTb[2 * 6656];     // 26,624 B (one buf per group)
    int tid = threadIdx.x;
    int n = blockIdx.y, ch = blockIdx.x;
    int p0 = ch * 125;
    const float* xn = x + n * CTV_;

    // staging: 41 elems/thread, batches of 8 loads in flight
    for (int g = 0; g < 5; ++g) {
        float vb[8]; int ib[8];
#pragma unroll
        for (int u = 0; u < 8; ++u) {
            int jj = tid + (g * 8 + u) * 512;
            int c = jj / 328, rr = jj - c * 328;
            int pp = p0 - 100 + rr;
            vb[u] = (pp >= 0 && pp < TV_) ? xn[c * TV_ + pp] : 0.f;
            ib[u] = rr * 72 + c;
        }
#pragma unroll
        for (int u = 0; u < 8; ++u) xs[ib[u]] = f2bf(vb[u]);
    }
    {
        int jj = tid + 40 * 512;
        int c = jj / 328, rr = jj - c * 328;
        int pp = p0 - 100 + rr;
        xs[rr * 72 + c] = f2bf((pp >= 0 && pp < TV_) ? xn[c * TV_ + pp] : 0.f);
    }
    for (int jj = tid; jj < 6656; jj += 512) ((int*)fTb)[jj] = 0;
    __syncthreads();

    int wave = tid >> 6, lane = tid & 63;
    int wq = wave & 3, grp = wave >> 2;
    int pw = wq * 32;
    short* fb = fTb + grp * 6656;

    // ---- one-tap phase: 3 epilogue rounds (grp1 idles round 2) ----
    {
        f32x4 acc3[3][2][2];
#pragma unroll
        for (int p = 0; p < 3; ++p)
#pragma unroll
            for (int h = 0; h < 2; ++h)
#pragma unroll
                for (int nt = 0; nt < 2; ++nt) acc3[p][h][nt] = (f32x4)(0.f);
        if (grp == 0) {
            const int PL[3] = {0, 2, 3};
            conv_onetap<3>(PL, wpk_all, xs, pw, lane, acc3);
        } else {
            const int PL[2] = {6, 8};
            conv_onetap<2>(PL, wpk_all, xs, pw, lane, acc3);
        }
        const int pl0[3] = {0, 2, 3}, pl1[3] = {6, 8, 0};
        int npair = (grp == 0) ? 3 : 2;
#pragma unroll
        for (int r = 0; r < 3; ++r) {
            bool valid = r < npair;
            int pair = (grp == 0) ? pl0[r] : pl1[r];
            if (valid) fT_write(acc3[r], pair, fb, bpk, wq, lane);
            __syncthreads();
            if (valid) gram_store(fb, pair, Gpart, n, ch, wq, lane);
            __syncthreads();
        }
    }

    // ---- nine-tap phase: 2 epilogue rounds ----
    {
        f32x4 acc2[2][2][2];
#pragma unroll
        for (int p = 0; p < 2; ++p)
#pragma unroll
            for (int h = 0; h < 2; ++h)
#pragma unroll
                for (int nt = 0; nt < 2; ++nt) acc2[p][h][nt] = (f32x4)(0.f);
        if (grp == 0) {
            const int PL[2] = {1, 4};
            conv_ninetap<2>(PL, wpk_all, xs, pw, lane, acc2);
        } else {
            const int PL[2] = {5, 7};
            conv_ninetap<2>(PL, wpk_all, xs, pw, lane, acc2);
        }
        const int plA[2] = {1, 4}, plB[2] = {5, 7};
#pragma unroll
        for (int r = 0; r < 2; ++r) {
            int pair = (grp == 0) ? plA[r] : plB[r];
            fT_write(acc2[r], pair, fb, bpk, wq, lane);
            __syncthreads();
            gram_store(fb, pair, Gpart, n, ch, wq, lane);
            __syncthreads();
        }
    }
}

// ---------------- gram finalize: coalesced unrolled sum + column softmax ----------------
__global__ __launch_bounds__(256) void gram_finalize_all(
    const short* __restrict__ Gpart, float* __restrict__ S) {
    __shared__ float sm[625];
    int n = blockIdx.x, pair = blockIdx.y;
    int tid = threadIdx.x;
    const short* g = Gpart + (pair * 64 + n) * 60 * 625;
    for (int qq = tid; qq < 625; qq += 256) {
        float s = 0.f;
#pragma unroll
        for (int ch = 0; ch < 60; ++ch) s += bf2f(g[ch * 625 + qq]);
        sm[qq] = s * (1.f / 4800.f);
    }
    __syncthreads();
    if (tid < 25) {
        int col = tid;
        float m = -1e30f;
#pragma unroll
        for (int r = 0; r < 25; ++r) m = fmaxf(m, sm[r * 25 + col]);
        float e[25];
        float sum = 0.f;
#pragma unroll
        for (int r = 0; r < 25; ++r) { e[r] = __expf(sm[r * 25 + col] - m); sum += e[r]; }
        float inv = 1.f / sum;
#pragma unroll
        for (int r = 0; r < 25; ++r)
            S[pair * 40000 + n * 625 + r * 25 + col] = e[r] * inv;
    }
}

// ---------------- aprep: per-n mixed A matrices -> bf16 B-frag layout ----------------
__global__ __launch_bounds__(256) void aprep(
    const float* __restrict__ amix, const float* __restrict__ S,
    const float* __restrict__ wts, short* __restrict__ apk) {
    int n = blockIdx.x;
    int tid = threadIdx.x;
    float w5 = wts[5], w6 = wts[6], w7 = wts[7];
#pragma unroll
    for (int it = 0; it < 15; ++it) {
        int jj = tid + it * 256;
        int i = jj / 1280;
        int rem = jj - i * 1280;
        int v = rem / 40, vp = rem - v * 40;
        float val = 0.f;
        if (v < 25 && vp < 25) {
            int e = vp * 25 + v;
            val = amix[i * 625 + e]
                + w5 * S[(i * 3 + 0) * 40000 + n * 625 + e]
                + w6 * S[(i * 3 + 1) * 40000 + n * 625 + e]
                + w7 * S[(i * 3 + 2) * 40000 + n * 625 + e];
        }
        apk[n * 3840 + jj] = f2bf(val);
    }
}

// ---------------- mega: y = sum_i (dw_i @ x) @ Ai, all subsets, + BN partials ----------------
__global__ __launch_bounds__(256, 3) void mega(
    const float* __restrict__ x, const short* __restrict__ apk,
    const short* __restrict__ dwpk, const float* __restrict__ db_sum,
    float* __restrict__ out, float* __restrict__ partials) {
    __shared__ __align__(16) short xs[80 * 72];       // 11,520 B
    __shared__ __align__(16) short us[3 * 64 * 104];  // 39,936 B

    int tid = threadIdx.x;
    int n = blockIdx.y;
    int t0 = blockIdx.x * 3;
    const float* xn = x + n * CTV_ + t0 * 25;

    int wave = tid >> 6, lane = tid & 63;
    int q = lane >> 4, m = lane & 15;

    // per-lane fragment loads from global (issued early, latency hidden by staging)
    short8 af[3][2];
#pragma unroll
    for (int mt = 0; mt < 3; ++mt)
#pragma unroll
        for (int kk = 0; kk < 2; ++kk)
            af[mt][kk] = *(const short8*)(dwpk + ((wave * 3 + mt) * 2 + kk) * 512 + lane * 8);
    const short* an = apk + n * 3840;
    short8 bfr[3][2];
#pragma unroll
    for (int i = 0; i < 3; ++i)
#pragma unroll
        for (int nt = 0; nt < 2; ++nt)
            bfr[i][nt] = *(const short8*)(an + (i * 32 + nt * 16 + m) * 40 + q * 8);
    float db4[4];
#pragma unroll
    for (int r = 0; r < 4; ++r) db4[r] = db_sum[wave * 16 + q * 4 + r];

    // batched staging: 20 elems/thread, 2 groups of 10
    {
        float vb[10]; int ib[10];
        for (int g = 0; g < 2; ++g) {
#pragma unroll
            for (int u = 0; u < 10; ++u) {
                int jj = tid + (g * 10 + u) * 256;
                int c = jj / 80, p = jj - c * 80;
                vb[u] = (p < 75) ? xn[c * TV_ + p] : 0.f;
                ib[u] = p * 72 + c;
            }
#pragma unroll
            for (int u = 0; u < 10; ++u) xs[ib[u]] = f2bf(vb[u]);
        }
    }
    for (int jj = tid; jj < 3 * 64 * 52; jj += 256) ((int*)us)[jj] = 0;

    __syncthreads();

    f32x4 acc[3][5];
#pragma unroll
    for (int mt = 0; mt < 3; ++mt)
#pragma unroll
        for (int nt = 0; nt < 5; ++nt) acc[mt][nt] = (f32x4)(0.f);

#pragma unroll
    for (int nt = 0; nt < 5; ++nt) {
        short8 b0 = *(const short8*)(xs + (nt * 16 + m) * 72 + q * 8);
        short8 b1 = *(const short8*)(xs + (nt * 16 + m) * 72 + 32 + q * 8);
#pragma unroll
        for (int mt = 0; mt < 3; ++mt) {
            acc[mt][nt] = __builtin_amdgcn_mfma_f32_16x16x32_bf16(af[mt][0], b0, acc[mt][nt], 0, 0, 0);
            acc[mt][nt] = __builtin_amdgcn_mfma_f32_16x16x32_bf16(af[mt][1], b1, acc[mt][nt], 0, 0, 0);
        }
    }
#pragma unroll
    for (int nt = 0; nt < 5; ++nt) {
        int p = nt * 16 + m;
        if (p < 75) {
            int t = p / 25, vp = p - t * 25;
            int base = t * 6656 + vp;
#pragma unroll
            for (int mt = 0; mt < 3; ++mt) {
#pragma unroll
                for (int r = 0; r < 4; ++r) {
                    int R = wave * 48 + mt * 16 + q * 4 + r;
                    int i = R >> 6, o = R & 63;
                    us[base + o * 104 + i * 32] = f2bf(acc[mt][nt][r]);
                }
            }
        }
    }
    __syncthreads();

    float sr[4] = {0.f, 0.f, 0.f, 0.f}, s2r[4] = {0.f, 0.f, 0.f, 0.f};
    float* yb = out + n * CTV_ + t0 * 25;
#pragma unroll
    for (int t = 0; t < 3; ++t) {
        f32x4 a2[2];
        a2[0] = (f32x4)(0.f);
        a2[1] = (f32x4)(0.f);
#pragma unroll
        for (int i = 0; i < 3; ++i) {
            short8 ua = *(const short8*)(us + t * 6656 + (wave * 16 + m) * 104 + i * 32 + q * 8);
            a2[0] = __builtin_amdgcn_mfma_f32_16x16x32_bf16(ua, bfr[i][0], a2[0], 0, 0, 0);
            a2[1] = __builtin_amdgcn_mfma_f32_16x16x32_bf16(ua, bfr[i][1], a2[1], 0, 0, 0);
        }
#pragma unroll
        for (int nt = 0; nt < 2; ++nt) {
            int v = nt * 16 + m;
            if (v < 25) {
#pragma unroll
                for (int r = 0; r < 4; ++r) {
                    int o = wave * 16 + q * 4 + r;
                    float val = a2[nt][r] + db4[r];
                    yb[o * TV_ + t * 25 + v] = val;
                    sr[r] += val;
                    s2r[r] += val * val;
                }
            }
        }
    }

    int bid = blockIdx.y * 100 + blockIdx.x;
#pragma unroll
    for (int r = 0; r < 4; ++r) {
        float s = sr[r], s2 = s2r[r];
#pragma unroll
        for (int d = 1; d < 16; d <<= 1) {
            s += __shfl_xor(s, d, 64);
            s2 += __shfl_xor(s2, d, 64);
        }
        if (m == 0) {
            int o = wave * 16 + q * 4 + r;
            partials[o * NB_ + bid] = s;
            partials[(64 + o) * NB_ + bid] = s2;
        }
    }
}

// ---------------- BN stats: sum partials ----------------
__global__ __launch_bounds__(256) void bn_stats(const float* __restrict__ partials,
                                                float* __restrict__ stats) {
    int j = blockIdx.x;
    int tid = threadIdx.x;
    float s = 0.f;
    for (int idx = tid; idx < NB_; idx += 256) s += partials[j * NB_ + idx];
    for (int d = 32; d > 0; d >>= 1) s += __shfl_down(s, d, 64);
    __shared__ float ls[4];
    if ((tid & 63) == 0) ls[tid >> 6] = s;
    __syncthreads();
    if (tid == 0) stats[j] = ls[0] + ls[1] + ls[2] + ls[3];
}

// ---------------- BN apply + residual + relu, float4 (TV_ % 4 == 0) ----------------
__global__ __launch_bounds__(256) void bn_final4(
    const float* __restrict__ x, const float* __restrict__ stats,
    const float* __restrict__ bnw, const float* __restrict__ bnb,
    float* __restrict__ y) {
    int idx = blockIdx.x * 256 + threadIdx.x;   // 7,680,000 float4s
    int o = (idx / 1875) & 63;                  // TV_/4 = 1875
    const float cnt = (float)(N_ * TV_);
    float mu = stats[o] / cnt;
    float var = stats[64 + o] / cnt - mu * mu;
    float inv = rsqrtf(var + 1e-5f);
    float w = bnw[o], b = bnb[o];
    f32x4 yv = ((const f32x4*)y)[idx];
    f32x4 xv = ((const f32x4*)x)[idx];
    f32x4 r;
#pragma unroll
    for (int k = 0; k < 4; ++k) r[k] = fmaxf((yv[k] - mu) * inv * w + b + xv[k], 0.f);
    ((f32x4*)y)[idx] = r;
}

extern "C" void kernel_launch(void* const* d_in, const int* in_sizes, int n_in,
                              void* d_out, int out_size, void* d_ws, size_t ws_size,
                              hipStream_t stream) {
    (void)in_sizes; (void)n_in; (void)out_size; (void)ws_size;
    const float* x     = (const float*)d_in[0];
    const float* wts   = (const float*)d_in[1];
    const float* A     = (const float*)d_in[2];
    const float* a_w   = (const float*)d_in[3];
    const float* a_b   = (const float*)d_in[4];
    const float* b_w   = (const float*)d_in[5];
    const float* b_b   = (const float*)d_in[6];
    const float* d_wp  = (const float*)d_in[7];
    const float* d_bp  = (const float*)d_in[8];
    const float* t1_w  = (const float*)d_in[9];
    const float* t1_b  = (const float*)d_in[10];
    const float* t2_w  = (const float*)d_in[11];
    const float* t2_b  = (const float*)d_in[12];
    const float* st11_w1 = (const float*)d_in[13];
    const float* st11_w9 = (const float*)d_in[14];
    const float* st11_b  = (const float*)d_in[15];
    const float* st12_w1 = (const float*)d_in[16];
    const float* st12_w9 = (const float*)d_in[17];
    const float* st12_b  = (const float*)d_in[18];
    const float* bn_w  = (const float*)d_in[19];
    const float* bn_b  = (const float*)d_in[20];
    float* out = (float*)d_out;

    // ---- workspace layout (disjoint) ----
    // amix      [0         , 7,500)
    // stats     [8,192     , 8,704)
    // db_sum    [12,288    , 12,544)
    // S         [16,384    , 1,456,384)     9 slabs x 160,000 B
    // dwpk      [1,460,224 , 1,484,800)
    // bpk       [1,486,848 , 1,488,000)     9 x 32 f32 biases
    // wpk_all   [1,490,944 , 1,822,720)     9 x 18432 bf16
    // Gpart     [2,097,152 , 45,297,152)    bf16 [9][64][60][625]
    // partials  [46,137,344, 49,414,144)    128 x 6400 f32
    // apk       [49,414,144, 49,905,664)    bf16 [64][3840]
    char* ws = (char*)d_ws;
    float* amix     = (float*)(ws);
    float* stats    = (float*)(ws + 8192);
    float* db_sum   = (float*)(ws + 12288);
    float* S        = (float*)(ws + 16384);
    short* dwpk     = (short*)(ws + 1460224);
    float* bpk      = (float*)(ws + 1486848);
    short* wpk_all  = (short*)(ws + 1490944);
    short* Gpart    = (short*)(ws + 2097152);
    float* partials = (float*)(ws + 46137344);
    short* apk      = (short*)(ws + 49414144);

    amix_kernel<<<1, 128, 0, stream>>>(A, wts, amix);
    dwprep<<<48, 256, 0, stream>>>(d_wp, d_bp, dwpk, db_sum);
    wprep_all<<<650, 256, 0, stream>>>(a_w, b_w, t1_w, t2_w, st11_w1, st12_w1,
                                       st11_w9, st12_w9, a_b, b_b, t1_b, t2_b,
                                       st11_b, st12_b, wpk_all, bpk);
    convgram<<<dim3(60, 64), 512, 0, stream>>>(x, wpk_all, bpk, Gpart);
    gram_finalize_all<<<dim3(64, 9), 256, 0, stream>>>(Gpart, S);
    aprep<<<64, 256, 0, stream>>>(amix, S, wts, apk);
    mega<<<dim3(100, 64), 256, 0, stream>>>(x, apk, dwpk, db_sum, out, partials);
    bn_stats<<<128, 256, 0, stream>>>(partials, stats);
    bn_final4<<<30000, 256, 0, stream>>>(x, stats, bn_w, bn_b, out);
}